// Round 4
// baseline (715.754 us; speedup 1.0000x reference)
//
#include <hip/hip_runtime.h>
#include <hip/hip_bf16.h>

#define T 2048
#define NR 1024
#define TOPK 40

static __device__ __forceinline__ float bnscale() { return 0.9999950000374997f; } // 1/sqrt(1+1e-5)

// wave64 max via DPP (VALU pipe, no LDS traffic), result broadcast via readlane
static __device__ __forceinline__ float wave_max64(float x) {
  float r = x; int t;
  t = __builtin_amdgcn_update_dpp(__float_as_int(r), __float_as_int(r), 0x111, 0xf, 0xf, false); r = fmaxf(r, __int_as_float(t)); // row_shr:1
  t = __builtin_amdgcn_update_dpp(__float_as_int(r), __float_as_int(r), 0x112, 0xf, 0xf, false); r = fmaxf(r, __int_as_float(t)); // row_shr:2
  t = __builtin_amdgcn_update_dpp(__float_as_int(r), __float_as_int(r), 0x114, 0xf, 0xf, false); r = fmaxf(r, __int_as_float(t)); // row_shr:4
  t = __builtin_amdgcn_update_dpp(__float_as_int(r), __float_as_int(r), 0x118, 0xf, 0xf, false); r = fmaxf(r, __int_as_float(t)); // row_shr:8
  t = __builtin_amdgcn_update_dpp(__float_as_int(r), __float_as_int(r), 0x142, 0xf, 0xf, false); r = fmaxf(r, __int_as_float(t)); // row_bcast:15
  t = __builtin_amdgcn_update_dpp(__float_as_int(r), __float_as_int(r), 0x143, 0xf, 0xf, false); r = fmaxf(r, __int_as_float(t)); // row_bcast:31
  return __int_as_float(__builtin_amdgcn_readlane(__float_as_int(r), 63));
}

// ---------------------------------------------------------------- kernel 1: bn -> conv q,k (k=3) + v (k=1)
// t-major q_t/k_t/v_t + c-major region means q_rc/k_rc
__global__ __launch_bounds__(256) void k_qkv(
    const float* __restrict__ x, const float* __restrict__ n1_g, const float* __restrict__ n1_b,
    const float* __restrict__ wq, const float* __restrict__ bnq_g, const float* __restrict__ bnq_b,
    const float* __restrict__ wk, const float* __restrict__ bnk_g, const float* __restrict__ bnk_b,
    const float* __restrict__ wv,
    float* __restrict__ q_t, float* __restrict__ k_t, float* __restrict__ v_t,
    float* __restrict__ q_rc, float* __restrict__ k_rc)
{
  const int b = blockIdx.y;
  const int t0 = blockIdx.x * 64;
  const int r0 = blockIdx.x * 32;
  const int tid = threadIdx.x;
  const float INVS = bnscale();

  __shared__ float xn[64][67];   // [c][tt], tt covers t0-1 .. t0+64 (pad 67: stride 3 mod 32)
  __shared__ float ot[64][67];   // [c_out][t_local]

  for (int i = tid; i < 64 * 66; i += 256) {
    int c = i / 66, tt = i - c * 66;
    int t = t0 + tt - 1;
    float v = (t >= 0 && t < T) ? x[(size_t)(b * 64 + c) * T + t] : 0.f;
    xn[c][tt] = v * (n1_g[c] * INVS) + n1_b[c];
  }
  __syncthreads();

  const int w = tid >> 6, lane = tid & 63;
  const int ob = __builtin_amdgcn_readfirstlane(w);   // wave-uniform out-channel base -> SGPR weight loads

  float accq[16], acck[16], accv[16];
#pragma unroll
  for (int j = 0; j < 16; ++j) { accq[j] = 0.f; acck[j] = 0.f; accv[j] = 0.f; }

#pragma unroll 1
  for (int c0 = 0; c0 < 64; c0 += 4) {
    float xr[4][3];
#pragma unroll
    for (int cc = 0; cc < 4; ++cc) {
      xr[cc][0] = xn[c0 + cc][lane];
      xr[cc][1] = xn[c0 + cc][lane + 1];
      xr[cc][2] = xn[c0 + cc][lane + 2];
    }
#pragma unroll
    for (int o16 = 0; o16 < 16; ++o16) {
      int o = ob + (o16 << 2);
      const float* wqo = wq + o * 192 + c0 * 3;
      const float* wko = wk + o * 192 + c0 * 3;
      const float* wvo = wv + o * 64 + c0;
      float aq = accq[o16], ak = acck[o16], av = accv[o16];
#pragma unroll
      for (int cc = 0; cc < 4; ++cc) {
        aq += xr[cc][0] * wqo[cc * 3 + 0] + xr[cc][1] * wqo[cc * 3 + 1] + xr[cc][2] * wqo[cc * 3 + 2];
        ak += xr[cc][0] * wko[cc * 3 + 0] + xr[cc][1] * wko[cc * 3 + 1] + xr[cc][2] * wko[cc * 3 + 2];
        av += xr[cc][1] * wvo[cc];
      }
      accq[o16] = aq; acck[o16] = ak; accv[o16] = av;
    }
  }

  // ---- Q: bn, transpose-store, region means ----
#pragma unroll
  for (int o16 = 0; o16 < 16; ++o16) {
    int o = ob + (o16 << 2);
    ot[o][lane] = accq[o16] * (bnq_g[o] * INVS) + bnq_b[o];
  }
  __syncthreads();
  for (int i = tid; i < 4096; i += 256) {
    int c = i & 63, tt = i >> 6;
    q_t[((size_t)(b * T + t0 + tt)) * 64 + c] = ot[c][tt];
  }
  for (int i = tid; i < 2048; i += 256) {
    int rr = i & 31, c = i >> 5;
    q_rc[((size_t)(b * 64 + c)) * NR + r0 + rr] = 0.5f * (ot[c][2 * rr] + ot[c][2 * rr + 1]);
  }
  __syncthreads();

  // ---- K ----
#pragma unroll
  for (int o16 = 0; o16 < 16; ++o16) {
    int o = ob + (o16 << 2);
    ot[o][lane] = acck[o16] * (bnk_g[o] * INVS) + bnk_b[o];
  }
  __syncthreads();
  for (int i = tid; i < 4096; i += 256) {
    int c = i & 63, tt = i >> 6;
    k_t[((size_t)(b * T + t0 + tt)) * 64 + c] = ot[c][tt];
  }
  for (int i = tid; i < 2048; i += 256) {
    int rr = i & 31, c = i >> 5;
    k_rc[((size_t)(b * 64 + c)) * NR + r0 + rr] = 0.5f * (ot[c][2 * rr] + ot[c][2 * rr + 1]);
  }
  __syncthreads();

  // ---- V ----
#pragma unroll
  for (int o16 = 0; o16 < 16; ++o16) {
    int o = ob + (o16 << 2);
    ot[o][lane] = accv[o16];
  }
  __syncthreads();
  for (int i = tid; i < 4096; i += 256) {
    int c = i & 63, tt = i >> 6;
    v_t[((size_t)(b * T + t0 + tt)) * 64 + c] = ot[c][tt];
  }
}

// ---------------------------------------------------------------- kernel 2: region scores + top-40 (register GEMM, DPP argmax)
// wave w owns row r0+w; lane holds 16 cols in registers; no score matrix in LDS.
__global__ __launch_bounds__(256) void k_scores(
    const float* __restrict__ q_rc, const float* __restrict__ k_rc, int* __restrict__ sel)
{
  const int b = blockIdx.y;
  const int r0 = blockIdx.x * 4;
  const int tid = threadIdx.x;
  const int w = tid >> 6, lane = tid & 63;

  __shared__ float qsT[4][64];            // [row][c]
  __shared__ float lv[16][4][64];         // sorted candidate values [slot][wave][lane]
  __shared__ unsigned short li[16][4][64];// sorted candidate col indices

  {
    int c = tid >> 2, rr = tid & 3;
    qsT[rr][c] = q_rc[((size_t)(b * 64 + c)) * NR + r0 + rr];
  }
  __syncthreads();

  // ---- GEMM: lane computes cols {256j + 4*lane + s}, j=0..3, s=0..3, of row r0+w
  float4 acc0 = {0,0,0,0}, acc1 = {0,0,0,0}, acc2 = {0,0,0,0}, acc3 = {0,0,0,0};
  const float4* kp = (const float4*)(k_rc + ((size_t)b * 64) * NR);
#pragma unroll 4
  for (int c0 = 0; c0 < 64; c0 += 4) {
    float4 qv = *(const float4*)&qsT[w][c0];
    float qarr[4] = {qv.x, qv.y, qv.z, qv.w};
#pragma unroll
    for (int cc = 0; cc < 4; ++cc) {
      const float4* kr = kp + (size_t)(c0 + cc) * 256 + lane;
      float4 k0 = kr[0], k1 = kr[64], k2 = kr[128], k3 = kr[192];
      float qf = qarr[cc];
      acc0.x += qf * k0.x; acc0.y += qf * k0.y; acc0.z += qf * k0.z; acc0.w += qf * k0.w;
      acc1.x += qf * k1.x; acc1.y += qf * k1.y; acc1.z += qf * k1.z; acc1.w += qf * k1.w;
      acc2.x += qf * k2.x; acc2.y += qf * k2.y; acc2.z += qf * k2.z; acc2.w += qf * k2.w;
      acc3.x += qf * k3.x; acc3.y += qf * k3.y; acc3.z += qf * k3.z; acc3.w += qf * k3.w;
    }
  }

  // ---- per-lane bitonic sort-16 (descending) in registers, value+index
  float sv[16]; int si[16];
  sv[0]=acc0.x; sv[1]=acc0.y; sv[2]=acc0.z; sv[3]=acc0.w;
  sv[4]=acc1.x; sv[5]=acc1.y; sv[6]=acc1.z; sv[7]=acc1.w;
  sv[8]=acc2.x; sv[9]=acc2.y; sv[10]=acc2.z; sv[11]=acc2.w;
  sv[12]=acc3.x; sv[13]=acc3.y; sv[14]=acc3.z; sv[15]=acc3.w;
#pragma unroll
  for (int j = 0; j < 4; ++j)
#pragma unroll
    for (int s = 0; s < 4; ++s)
      si[4*j+s] = 256*j + 4*lane + s;

#pragma unroll
  for (int k = 2; k <= 16; k <<= 1) {
#pragma unroll
    for (int j = k >> 1; j > 0; j >>= 1) {
#pragma unroll
      for (int i = 0; i < 16; ++i) {
        int l = i ^ j;
        if (l > i) {
          bool dir = ((i & k) == 0);  // flipped comparator -> overall descending
          bool sw = dir ? (sv[i] < sv[l]) : (sv[i] > sv[l]);
          float tv = sw ? sv[l] : sv[i]; sv[l] = sw ? sv[i] : sv[l]; sv[i] = tv;
          int   ti = sw ? si[l] : si[i]; si[l] = sw ? si[i] : si[l]; si[i] = ti;
        }
      }
    }
  }

  // spill sorted lists (wave-private; no barrier needed, same-wave LDS RAW handled by waitcnt)
#pragma unroll
  for (int s = 0; s < 16; ++s) {
    lv[s][w][lane] = sv[s];
    li[s][w][lane] = (unsigned short)si[s];
  }

  // ---- 40 iterations of wave argmax via DPP; winner emits + pops
  float m1 = sv[0]; int i1 = si[0]; int p = 1;
  int* srow = sel + ((size_t)(b * NR + r0 + w)) * TOPK;
  for (int it = 0; it < TOPK; ++it) {
    float bv = wave_max64(m1);
    unsigned long long ball = __ballot(m1 == bv);
    int wl = (int)__builtin_ctzll(ball);
    if (lane == wl) {
      srow[it] = i1;
      if (p < 16) {
        m1 = lv[p][w][lane];
        i1 = (int)li[p][w][lane];
        ++p;
      } else {
        m1 = -INFINITY;
      }
    }
  }
}

// ---------------------------------------------------------------- kernel 3: gathered attention + lepe depthwise + bias
// K staged in LDS; V consumed directly from global (coalesced row reads); ~26KB LDS -> 6 blocks/CU
__global__ __launch_bounds__(256) void k_attn(
    const float* __restrict__ q_t, const float* __restrict__ k_t, const float* __restrict__ v_t,
    const int* __restrict__ sel, const float* __restrict__ lepe_w, const float* __restrict__ lepe_b,
    float* __restrict__ o_t)
{
  const int b = blockIdx.y;
  const int r = blockIdx.x;
  const int tid = threadIdx.x;

  __shared__ float kg[80][65];      // gathered K, 20.8 KB
  __shared__ float qb[2][64];
  __shared__ int   sl[40];
  __shared__ float lg[4][2][84];    // probs per head
  __shared__ float vl[4][64];       // v rows 2r-1..2r+2 for lepe
  __shared__ float part[2][2][64];  // PV partials [half][sq][c]

  if (tid < 40) sl[tid] = sel[((size_t)(b * NR + r)) * TOPK + tid];
  if (tid >= 128 && tid < 256) {
    int i = tid - 128;
    int s = i >> 6, c = i & 63;
    qb[s][c] = q_t[((size_t)(b * T + r * 2 + s)) * 64 + c];
  }
  {
    int idx = tid >> 6, c = tid & 63;
    int t = 2 * r - 1 + idx;
    vl[idx][c] = (t >= 0 && t < T) ? v_t[((size_t)(b * T + t)) * 64 + c] : 0.f;
  }
  __syncthreads();

  for (int i = tid; i < 80 * 64; i += 256) {
    int row = i >> 6, c = i & 63;
    int t = sl[row >> 1] * 2 + (row & 1);
    kg[row][c] = k_t[((size_t)(b * T + t)) * 64 + c];
  }
  __syncthreads();

  const int h = tid >> 6, lane = tid & 63;

  // QK^T: wave h computes its head's 2x80 logits
  for (int flat = lane; flat < 160; flat += 64) {
    int sq = flat / 80;
    int col = flat - sq * 80;
    float acc = 0.f;
#pragma unroll
    for (int d = 0; d < 16; ++d) acc += qb[sq][h * 16 + d] * kg[col][h * 16 + d];
    lg[h][sq][col] = acc * 0.125f;  // 64^-0.5
  }

  // softmax (wave-local: lg[h] written and read by wave h only)
  for (int sq = 0; sq < 2; ++sq) {
    float a = lg[h][sq][lane];
    float bb = (lane < 16) ? lg[h][sq][64 + lane] : -INFINITY;
    float m = fmaxf(a, bb);
    for (int mm = 32; mm >= 1; mm >>= 1) m = fmaxf(m, __shfl_xor(m, mm));
    float ea = expf(a - m);
    float eb = (lane < 16) ? expf(bb - m) : 0.f;
    float ssum = ea + eb;
    for (int mm = 32; mm >= 1; mm >>= 1) ssum += __shfl_xor(ssum, mm);
    float inv = 1.f / ssum;
    lg[h][sq][lane] = ea * inv;
    if (lane < 16) lg[h][sq][64 + lane] = eb * inv;
  }
  __syncthreads();

  // PV: thread = (half, sq, c); V rows read coalesced from global
  {
    const int c = tid & 63, j = tid >> 6;
    const int sq = j & 1, half = j >> 1;
    const float* vbase = v_t + ((size_t)b * T) * 64 + c;
    const int hh = c >> 4;
    float acc = 0.f;
#pragma unroll 4
    for (int cc = 0; cc < 40; ++cc) {
      int col = half * 40 + cc;
      int t = sl[col >> 1] * 2 + (col & 1);
      acc += lg[hh][sq][col] * vbase[(size_t)t * 64];
    }
    part[half][sq][c] = acc;
  }
  __syncthreads();

  if (tid < 128) {
    int sq = tid >> 6, c = tid & 63;
    float o = part[0][sq][c] + part[1][sq][c];
    float lep = lepe_b[c];
#pragma unroll
    for (int kk = 0; kk < 3; ++kk) lep += lepe_w[c * 3 + kk] * vl[sq + kk][c];
    o_t[((size_t)(b * T + 2 * r + sq)) * 64 + c] = o + lep;
  }
}

// ---------------------------------------------------------------- kernel 4: out conv + residual + bn2 + fc1 + relu -> h_c (c-major)
__global__ __launch_bounds__(256) void k_mix(
    const float* __restrict__ x, const float* __restrict__ o_t,
    const float* __restrict__ out_w, const float* __restrict__ out_b,
    const float* __restrict__ n2_g, const float* __restrict__ n2_b,
    const float* __restrict__ fc1_w, const float* __restrict__ bn1_g, const float* __restrict__ bn1_b,
    float* __restrict__ xres, float* __restrict__ h_c)
{
  const int b = blockIdx.y;
  const int t0 = blockIdx.x * 16;
  const int tid = threadIdx.x;
  const float INVS = bnscale();

  __shared__ float ol[16][65];
  __shared__ float yn[16][65];
  __shared__ float xl[16][65];
  __shared__ float wo[64][65];    // out_w transposed: wo[cc][c]
  __shared__ float w1[128][65];   // fc1_w natural [cc][c]
  __shared__ float res2[128][17];

  for (int i = tid; i < 1024; i += 256) {
    int tt = i >> 6, c = i & 63;
    ol[tt][c] = o_t[((size_t)(b * T + t0 + tt)) * 64 + c];
  }
  for (int i = tid; i < 1024; i += 256) {
    int c = i >> 4, tt = i & 15;
    xl[tt][c] = x[(size_t)(b * 64 + c) * T + t0 + tt];
  }
  for (int i = tid; i < 4096; i += 256) {
    int c = i >> 6, cc = i & 63;
    wo[cc][c] = out_w[i];
  }
  for (int i = tid; i < 8192; i += 256) {
    int cc = i >> 6, c = i & 63;
    w1[cc][c] = fc1_w[i];
  }
  __syncthreads();

  // out conv: thread = (c, 4 tt's)
  {
    const int c = tid & 63, grp = tid >> 6;
    float a0 = out_b[c], a1 = a0, a2 = a0, a3 = a0;
    for (int cc = 0; cc < 64; ++cc) {
      float wv = wo[cc][c];
      a0 += wv * ol[grp * 4 + 0][cc];
      a1 += wv * ol[grp * 4 + 1][cc];
      a2 += wv * ol[grp * 4 + 2][cc];
      a3 += wv * ol[grp * 4 + 3][cc];
    }
    float g2 = n2_g[c] * INVS, b2 = n2_b[c];
    float av[4] = {a0, a1, a2, a3};
#pragma unroll
    for (int j = 0; j < 4; ++j) {
      int tt = grp * 4 + j;
      float xr = xl[tt][c] + av[j];
      xres[((size_t)(b * T + t0 + tt)) * 64 + c] = xr;
      yn[tt][c] = xr * g2 + b2;
    }
  }
  __syncthreads();

  // fc1 + bn1 + relu: thread = (cc, 8 tt's)
  {
    const int cc = tid & 127, half = tid >> 7;
    float acc[8];
#pragma unroll
    for (int j = 0; j < 8; ++j) acc[j] = 0.f;
    for (int c = 0; c < 64; ++c) {
      float wv = w1[cc][c];
#pragma unroll
      for (int j = 0; j < 8; ++j) acc[j] += wv * yn[half * 8 + j][c];
    }
    float g1 = bn1_g[cc] * INVS, b1 = bn1_b[cc];
#pragma unroll
    for (int j = 0; j < 8; ++j)
      res2[cc][half * 8 + j] = fmaxf(acc[j] * g1 + b1, 0.f);
  }
  __syncthreads();

  for (int i = tid; i < 2048; i += 256) {
    int tt = i & 15, cc = i >> 4;
    h_c[((size_t)(b * 128 + cc)) * T + t0 + tt] = res2[cc][tt];
  }
}

// ---------------------------------------------------------------- kernel 5: FFT(DIF) -> diag filter + relu -> iFFT(DIT), c-major I/O
__global__ __launch_bounds__(256) void k_fft(
    const float* __restrict__ h_c, const float* __restrict__ fr, const float* __restrict__ fi,
    const float* __restrict__ frb, const float* __restrict__ fib, float* __restrict__ g_c)
{
  const int b = blockIdx.y;
  const int c2 = blockIdx.x;
  const int tid = threadIdx.x;

  __shared__ float re[2048];
  __shared__ float im[2048];
  __shared__ float twr[1024];
  __shared__ float twi[1024];

  for (int i = tid; i < 1024; i += 256) {
    float ang = -6.283185307179586f * (float)i * (1.0f / 2048.0f);
    float sn, cs;
    sincosf(ang, &sn, &cs);
    twr[i] = cs; twi[i] = sn;
  }
  const float* hrow = h_c + ((size_t)(b * 128 + c2)) * T;
  for (int t = tid; t < 2048; t += 256) {
    re[t] = hrow[t];
    im[t] = 0.f;
  }
  __syncthreads();

  // forward DIF: natural in -> bit-reversed out
  for (int s = 11; s >= 1; --s) {
    const int half = 1 << (s - 1);
    for (int k = tid; k < 1024; k += 256) {
      int pos = k & (half - 1);
      int grp = k >> (s - 1);
      int i0 = (grp << s) + pos;
      int i1 = i0 + half;
      int j = pos << (11 - s);
      float wr = twr[j], wi = twi[j];
      float ur = re[i0], ui = im[i0];
      float vr = re[i1], vi = im[i1];
      re[i0] = ur + vr; im[i0] = ui + vi;
      float dr = ur - vr, di = ui - vi;
      re[i1] = dr * wr - di * wi;
      im[i1] = dr * wi + di * wr;
    }
    __syncthreads();
  }

  // elementwise spectral filter (order-independent)
  const float SC = 0.022097086912079608f; // 1/sqrt(2048)
  const float fa = fr[c2 * 129];
  const float fb = fi[c2 * 129];
  const float fra = frb[c2];
  const float fia = fib[c2];
  for (int t = tid; t < 2048; t += 256) {
    float rr = re[t] * SC, ii = im[t] * SC;
    re[t] = fmaxf(rr * fa - ii * fb + fra, 0.f);
    im[t] = fmaxf(ii * fa + rr * fb + fia, 0.f);
  }
  __syncthreads();

  // inverse DIT: bit-reversed in -> natural out
  for (int s = 1; s <= 11; ++s) {
    const int half = 1 << (s - 1);
    for (int k = tid; k < 1024; k += 256) {
      int pos = k & (half - 1);
      int grp = k >> (s - 1);
      int i0 = (grp << s) + pos;
      int i1 = i0 + half;
      int j = pos << (11 - s);
      float wr = twr[j], wi = -twi[j];
      float xr = re[i1], xi = im[i1];
      float tr = xr * wr - xi * wi;
      float ti = xr * wi + xi * wr;
      float ur = re[i0], ui = im[i0];
      re[i0] = ur + tr; im[i0] = ui + ti;
      re[i1] = ur - tr; im[i1] = ui - ti;
    }
    __syncthreads();
  }

  float* grow = g_c + ((size_t)(b * 128 + c2)) * T;
  for (int t = tid; t < 2048; t += 256)
    grow[t] = re[t] * SC;
}

// ---------------------------------------------------------------- kernel 6: fc2 + bn + final residual -> d_out (B,64,T)
__global__ __launch_bounds__(256) void k_out(
    const float* __restrict__ g_c, const float* __restrict__ xres,
    const float* __restrict__ fc2_w, const float* __restrict__ bn2_g, const float* __restrict__ bn2_b,
    float* __restrict__ out)
{
  const int b = blockIdx.y;
  const int t0 = blockIdx.x * 16;
  const int tid = threadIdx.x;
  const float INVS = bnscale();

  __shared__ float gl[16][129];
  __shared__ float w2[128][65];   // fc2_w transposed: w2[cc][c]
  __shared__ float res[64][17];

  for (int i = tid; i < 2048; i += 256) {
    int tt = i & 15, cc = i >> 4;
    gl[tt][cc] = g_c[((size_t)(b * 128 + cc)) * T + t0 + tt];
  }
  for (int i = tid; i < 8192; i += 256) {
    int c = i >> 7, cc = i & 127;
    w2[cc][c] = fc2_w[i];
  }
  __syncthreads();

  {
    const int c = tid & 63, grp = tid >> 6;
    float a0 = 0.f, a1 = 0.f, a2 = 0.f, a3 = 0.f;
    for (int cc = 0; cc < 128; ++cc) {
      float wv = w2[cc][c];
      a0 += wv * gl[grp * 4 + 0][cc];
      a1 += wv * gl[grp * 4 + 1][cc];
      a2 += wv * gl[grp * 4 + 2][cc];
      a3 += wv * gl[grp * 4 + 3][cc];
    }
    float g2 = bn2_g[c] * INVS, b2 = bn2_b[c];
    float av[4] = {a0, a1, a2, a3};
#pragma unroll
    for (int j = 0; j < 4; ++j) {
      int tt = grp * 4 + j;
      res[c][tt] = xres[((size_t)(b * T + t0 + tt)) * 64 + c] + av[j] * g2 + b2;
    }
  }
  __syncthreads();

  for (int i = tid; i < 1024; i += 256) {
    int tt = i & 15, c = i >> 4;
    out[(size_t)(b * 64 + c) * T + t0 + tt] = res[c][tt];
  }
}

// ----------------------------------------------------------------
extern "C" void kernel_launch(void* const* d_in, const int* in_sizes, int n_in,
                              void* d_out, int out_size, void* d_ws, size_t ws_size,
                              hipStream_t stream) {
  (void)in_sizes; (void)n_in; (void)out_size; (void)ws_size;
  const float* x     = (const float*)d_in[0];
  const float* n1_g  = (const float*)d_in[1];
  const float* n1_b  = (const float*)d_in[2];
  const float* wq    = (const float*)d_in[3];
  const float* bnq_g = (const float*)d_in[4];
  const float* bnq_b = (const float*)d_in[5];
  const float* wk    = (const float*)d_in[6];
  const float* bnk_g = (const float*)d_in[7];
  const float* bnk_b = (const float*)d_in[8];
  const float* wv    = (const float*)d_in[9];
  const float* lepe_w= (const float*)d_in[10];
  const float* lepe_b= (const float*)d_in[11];
  const float* out_w = (const float*)d_in[12];
  const float* out_b = (const float*)d_in[13];
  const float* n2_g  = (const float*)d_in[14];
  const float* n2_b  = (const float*)d_in[15];
  const float* fc1_w = (const float*)d_in[16];
  const float* bn1_g = (const float*)d_in[17];
  const float* bn1_b = (const float*)d_in[18];
  const float* fr    = (const float*)d_in[19];
  const float* fi    = (const float*)d_in[20];
  const float* frb   = (const float*)d_in[21];
  const float* fib   = (const float*)d_in[22];
  const float* fc2_w = (const float*)d_in[23];
  const float* bn2_g = (const float*)d_in[24];
  const float* bn2_b = (const float*)d_in[25];

  float* out = (float*)d_out;
  float* ws  = (float*)d_ws;
  const size_t M1 = (size_t)1 << 20;

  float* q_t  = ws;            // 2M floats
  float* k_t  = ws + 2 * M1;   // 2M
  float* v_t  = ws + 4 * M1;   // 2M
  float* q_rc = ws + 6 * M1;   // 1M  (c-major [b][c][r])
  float* k_rc = ws + 7 * M1;   // 1M
  float* o_t  = ws + 8 * M1;   // 2M
  float* xrs  = ws + 10 * M1;  // 2M
  int*   sel  = (int*)(ws + 12 * M1); // 0.64M ints
  float* h_c  = ws;            // 4M c-major [b][cc][t], reuses q_t+k_t (dead after k_attn)
  float* g_c  = ws + 4 * M1;   // 4M c-major, reuses v_t+q_rc+k_rc

  k_qkv<<<dim3(32, 16), 256, 0, stream>>>(x, n1_g, n1_b, wq, bnq_g, bnq_b,
                                          wk, bnk_g, bnk_b, wv, q_t, k_t, v_t, q_rc, k_rc);
  k_scores<<<dim3(256, 16), 256, 0, stream>>>(q_rc, k_rc, sel);
  k_attn<<<dim3(1024, 16), 256, 0, stream>>>(q_t, k_t, v_t, sel, lepe_w, lepe_b, o_t);
  k_mix<<<dim3(128, 16), 256, 0, stream>>>(x, o_t, out_w, out_b, n2_g, n2_b,
                                           fc1_w, bn1_g, bn1_b, xrs, h_c);
  k_fft<<<dim3(128, 16), 256, 0, stream>>>(h_c, fr, fi, frb, fib, g_c);
  k_out<<<dim3(128, 16), 256, 0, stream>>>(g_c, xrs, fc2_w, bn2_g, bn2_b, out);
}

// Round 5
// 596.023 us; speedup vs baseline: 1.2009x; 1.2009x over previous
//
#include <hip/hip_runtime.h>
#include <hip/hip_bf16.h>

#define T 2048
#define NR 1024
#define TOPK 40

static __device__ __forceinline__ float bnscale() { return 0.9999950000374997f; } // 1/sqrt(1+1e-5)

// wave64 unsigned max via DPP (VALU pipe only), broadcast via readlane(63)
static __device__ __forceinline__ unsigned wave_umax64(unsigned x) {
  unsigned r = x, t;
  t = (unsigned)__builtin_amdgcn_update_dpp((int)r, (int)r, 0x111, 0xf, 0xf, false); r = r > t ? r : t; // row_shr:1
  t = (unsigned)__builtin_amdgcn_update_dpp((int)r, (int)r, 0x112, 0xf, 0xf, false); r = r > t ? r : t; // row_shr:2
  t = (unsigned)__builtin_amdgcn_update_dpp((int)r, (int)r, 0x114, 0xf, 0xf, false); r = r > t ? r : t; // row_shr:4
  t = (unsigned)__builtin_amdgcn_update_dpp((int)r, (int)r, 0x118, 0xf, 0xf, false); r = r > t ? r : t; // row_shr:8
  t = (unsigned)__builtin_amdgcn_update_dpp((int)r, (int)r, 0x142, 0xf, 0xf, false); r = r > t ? r : t; // row_bcast:15
  t = (unsigned)__builtin_amdgcn_update_dpp((int)r, (int)r, 0x143, 0xf, 0xf, false); r = r > t ? r : t; // row_bcast:31
  return (unsigned)__builtin_amdgcn_readlane((int)r, 63);
}

// ---------------------------------------------------------------- kernel 1: bn -> conv q,k (k=3) + v (k=1)
// t-major q_t/k_t/v_t + c-major region means q_rc/k_rc
__global__ __launch_bounds__(256) void k_qkv(
    const float* __restrict__ x, const float* __restrict__ n1_g, const float* __restrict__ n1_b,
    const float* __restrict__ wq, const float* __restrict__ bnq_g, const float* __restrict__ bnq_b,
    const float* __restrict__ wk, const float* __restrict__ bnk_g, const float* __restrict__ bnk_b,
    const float* __restrict__ wv,
    float* __restrict__ q_t, float* __restrict__ k_t, float* __restrict__ v_t,
    float* __restrict__ q_rc, float* __restrict__ k_rc)
{
  const int b = blockIdx.y;
  const int t0 = blockIdx.x * 64;
  const int r0 = blockIdx.x * 32;
  const int tid = threadIdx.x;
  const float INVS = bnscale();

  __shared__ float xn[64][67];   // [c][tt], tt covers t0-1 .. t0+64 (pad 67: stride 3 mod 32)
  __shared__ float ot[64][67];   // [c_out][t_local]

  for (int i = tid; i < 64 * 66; i += 256) {
    int c = i / 66, tt = i - c * 66;
    int t = t0 + tt - 1;
    float v = (t >= 0 && t < T) ? x[(size_t)(b * 64 + c) * T + t] : 0.f;
    xn[c][tt] = v * (n1_g[c] * INVS) + n1_b[c];
  }
  __syncthreads();

  const int w = tid >> 6, lane = tid & 63;
  const int ob = __builtin_amdgcn_readfirstlane(w);   // wave-uniform out-channel base -> SGPR weight loads

  float accq[16], acck[16], accv[16];
#pragma unroll
  for (int j = 0; j < 16; ++j) { accq[j] = 0.f; acck[j] = 0.f; accv[j] = 0.f; }

#pragma unroll 1
  for (int c0 = 0; c0 < 64; c0 += 4) {
    float xr[4][3];
#pragma unroll
    for (int cc = 0; cc < 4; ++cc) {
      xr[cc][0] = xn[c0 + cc][lane];
      xr[cc][1] = xn[c0 + cc][lane + 1];
      xr[cc][2] = xn[c0 + cc][lane + 2];
    }
#pragma unroll
    for (int o16 = 0; o16 < 16; ++o16) {
      int o = ob + (o16 << 2);
      const float* wqo = wq + o * 192 + c0 * 3;
      const float* wko = wk + o * 192 + c0 * 3;
      const float* wvo = wv + o * 64 + c0;
      float aq = accq[o16], ak = acck[o16], av = accv[o16];
#pragma unroll
      for (int cc = 0; cc < 4; ++cc) {
        aq += xr[cc][0] * wqo[cc * 3 + 0] + xr[cc][1] * wqo[cc * 3 + 1] + xr[cc][2] * wqo[cc * 3 + 2];
        ak += xr[cc][0] * wko[cc * 3 + 0] + xr[cc][1] * wko[cc * 3 + 1] + xr[cc][2] * wko[cc * 3 + 2];
        av += xr[cc][1] * wvo[cc];
      }
      accq[o16] = aq; acck[o16] = ak; accv[o16] = av;
    }
  }

  // ---- Q: bn, transpose-store, region means ----
#pragma unroll
  for (int o16 = 0; o16 < 16; ++o16) {
    int o = ob + (o16 << 2);
    ot[o][lane] = accq[o16] * (bnq_g[o] * INVS) + bnq_b[o];
  }
  __syncthreads();
  for (int i = tid; i < 4096; i += 256) {
    int c = i & 63, tt = i >> 6;
    q_t[((size_t)(b * T + t0 + tt)) * 64 + c] = ot[c][tt];
  }
  for (int i = tid; i < 2048; i += 256) {
    int rr = i & 31, c = i >> 5;
    q_rc[((size_t)(b * 64 + c)) * NR + r0 + rr] = 0.5f * (ot[c][2 * rr] + ot[c][2 * rr + 1]);
  }
  __syncthreads();

  // ---- K ----
#pragma unroll
  for (int o16 = 0; o16 < 16; ++o16) {
    int o = ob + (o16 << 2);
    ot[o][lane] = acck[o16] * (bnk_g[o] * INVS) + bnk_b[o];
  }
  __syncthreads();
  for (int i = tid; i < 4096; i += 256) {
    int c = i & 63, tt = i >> 6;
    k_t[((size_t)(b * T + t0 + tt)) * 64 + c] = ot[c][tt];
  }
  for (int i = tid; i < 2048; i += 256) {
    int rr = i & 31, c = i >> 5;
    k_rc[((size_t)(b * 64 + c)) * NR + r0 + rr] = 0.5f * (ot[c][2 * rr] + ot[c][2 * rr + 1]);
  }
  __syncthreads();

  // ---- V ----
#pragma unroll
  for (int o16 = 0; o16 < 16; ++o16) {
    int o = ob + (o16 << 2);
    ot[o][lane] = accv[o16];
  }
  __syncthreads();
  for (int i = tid; i < 4096; i += 256) {
    int c = i & 63, tt = i >> 6;
    v_t[((size_t)(b * T + t0 + tt)) * 64 + c] = ot[c][tt];
  }
}

// ---------------------------------------------------------------- kernel 2: region scores + top-40
// register GEMM -> pack (22-bit sortable value | 10-bit 1023-idx) -> u32 sort-16 -> DPP umax serial-40
__global__ __launch_bounds__(256) void k_scores(
    const float* __restrict__ q_rc, const float* __restrict__ k_rc, int* __restrict__ sel)
{
  const int b = blockIdx.y;
  const int r0 = blockIdx.x * 4;
  const int tid = threadIdx.x;
  const int w = tid >> 6, lane = tid & 63;

  __shared__ float qsT[4][64];            // [row][c]
  __shared__ unsigned ll[16][4][64];      // packed sorted candidates [slot][wave][lane] (lane-contiguous)

  {
    int c = tid >> 2, rr = tid & 3;
    qsT[rr][c] = q_rc[((size_t)(b * 64 + c)) * NR + r0 + rr];
  }
  __syncthreads();

  // ---- GEMM: lane computes cols {256j + 4*lane + s}, j,s in 0..3, of row r0+w
  float4 acc0 = {0,0,0,0}, acc1 = {0,0,0,0}, acc2 = {0,0,0,0}, acc3 = {0,0,0,0};
  const float4* kp = (const float4*)(k_rc + ((size_t)b * 64) * NR);
#pragma unroll 4
  for (int c0 = 0; c0 < 64; c0 += 4) {
    float4 qv = *(const float4*)&qsT[w][c0];
    float qarr[4] = {qv.x, qv.y, qv.z, qv.w};
#pragma unroll
    for (int cc = 0; cc < 4; ++cc) {
      const float4* kr = kp + (size_t)(c0 + cc) * 256 + lane;
      float4 k0 = kr[0], k1 = kr[64], k2 = kr[128], k3 = kr[192];
      float qf = qarr[cc];
      acc0.x += qf * k0.x; acc0.y += qf * k0.y; acc0.z += qf * k0.z; acc0.w += qf * k0.w;
      acc1.x += qf * k1.x; acc1.y += qf * k1.y; acc1.z += qf * k1.z; acc1.w += qf * k1.w;
      acc2.x += qf * k2.x; acc2.y += qf * k2.y; acc2.z += qf * k2.z; acc2.w += qf * k2.w;
      acc3.x += qf * k3.x; acc3.y += qf * k3.y; acc3.z += qf * k3.z; acc3.w += qf * k3.w;
    }
  }

  // ---- pack into sortable u32: high 22 bits = sortable(score), low 10 = 1023-idx (lower idx wins ties)
  float sv[16];
  sv[0]=acc0.x; sv[1]=acc0.y; sv[2]=acc0.z; sv[3]=acc0.w;
  sv[4]=acc1.x; sv[5]=acc1.y; sv[6]=acc1.z; sv[7]=acc1.w;
  sv[8]=acc2.x; sv[9]=acc2.y; sv[10]=acc2.z; sv[11]=acc2.w;
  sv[12]=acc3.x; sv[13]=acc3.y; sv[14]=acc3.z; sv[15]=acc3.w;
  unsigned pk[16];
#pragma unroll
  for (int j = 0; j < 4; ++j) {
#pragma unroll
    for (int s = 0; s < 4; ++s) {
      int slot = 4 * j + s;
      unsigned u = __float_as_uint(sv[slot]);
      u ^= (unsigned)((int)u >> 31) | 0x80000000u;
      int idx = 256 * j + 4 * lane + s;
      pk[slot] = (u & 0xFFFFFC00u) | (unsigned)(1023 - idx);
    }
  }

  // ---- per-lane bitonic sort-16 descending on packed u32 (min/max only)
#pragma unroll
  for (int k = 2; k <= 16; k <<= 1) {
#pragma unroll
    for (int j = k >> 1; j > 0; j >>= 1) {
#pragma unroll
      for (int i = 0; i < 16; ++i) {
        int l = i ^ j;
        if (l > i) {
          unsigned hi = pk[i] > pk[l] ? pk[i] : pk[l];
          unsigned lo = pk[i] > pk[l] ? pk[l] : pk[i];
          bool dir = ((i & k) == 0);   // descending: larger at lower position
          pk[i] = dir ? hi : lo;
          pk[l] = dir ? lo : hi;
        }
      }
    }
  }

  // spill sorted list (wave-private; lane-contiguous, conflict-free)
#pragma unroll
  for (int s = 0; s < 16; ++s) ll[s][w][lane] = pk[s];

  // ---- serial top-40: DPP umax; winner unique by construction; head+next register pipeline
  unsigned m = pk[0], m2 = pk[1];
  int p = 2;
  int* srow = sel + ((size_t)(b * NR + r0 + w)) * TOPK;
  for (int it = 0; it < TOPK; ++it) {
    unsigned bv = wave_umax64(m);
    if (lane == 0) srow[it] = 1023 - (int)(bv & 1023u);
    if (m == bv) {               // exactly one lane matches
      m = m2;
      unsigned nxt = ll[p < 16 ? p : 15][w][lane];
      m2 = (p < 16) ? nxt : 0u;
      ++p;
    }
  }
}

// ---------------------------------------------------------------- kernel 3: gathered attention + lepe depthwise + bias
// K staged in LDS; V consumed directly from global (coalesced row reads); ~26KB LDS -> 6 blocks/CU
__global__ __launch_bounds__(256) void k_attn(
    const float* __restrict__ q_t, const float* __restrict__ k_t, const float* __restrict__ v_t,
    const int* __restrict__ sel, const float* __restrict__ lepe_w, const float* __restrict__ lepe_b,
    float* __restrict__ o_t)
{
  const int b = blockIdx.y;
  const int r = blockIdx.x;
  const int tid = threadIdx.x;

  __shared__ float kg[80][65];      // gathered K, 20.8 KB
  __shared__ float qb[2][64];
  __shared__ int   sl[40];
  __shared__ float lg[4][2][84];    // probs per head
  __shared__ float vl[4][64];       // v rows 2r-1..2r+2 for lepe
  __shared__ float part[2][2][64];  // PV partials [half][sq][c]

  if (tid < 40) sl[tid] = sel[((size_t)(b * NR + r)) * TOPK + tid];
  if (tid >= 128 && tid < 256) {
    int i = tid - 128;
    int s = i >> 6, c = i & 63;
    qb[s][c] = q_t[((size_t)(b * T + r * 2 + s)) * 64 + c];
  }
  {
    int idx = tid >> 6, c = tid & 63;
    int t = 2 * r - 1 + idx;
    vl[idx][c] = (t >= 0 && t < T) ? v_t[((size_t)(b * T + t)) * 64 + c] : 0.f;
  }
  __syncthreads();

  for (int i = tid; i < 80 * 64; i += 256) {
    int row = i >> 6, c = i & 63;
    int t = sl[row >> 1] * 2 + (row & 1);
    kg[row][c] = k_t[((size_t)(b * T + t)) * 64 + c];
  }
  __syncthreads();

  const int h = tid >> 6, lane = tid & 63;

  // QK^T: wave h computes its head's 2x80 logits
  for (int flat = lane; flat < 160; flat += 64) {
    int sq = flat / 80;
    int col = flat - sq * 80;
    float acc = 0.f;
#pragma unroll
    for (int d = 0; d < 16; ++d) acc += qb[sq][h * 16 + d] * kg[col][h * 16 + d];
    lg[h][sq][col] = acc * 0.125f;  // 64^-0.5
  }

  // softmax (wave-local: lg[h] written and read by wave h only)
  for (int sq = 0; sq < 2; ++sq) {
    float a = lg[h][sq][lane];
    float bb = (lane < 16) ? lg[h][sq][64 + lane] : -INFINITY;
    float m = fmaxf(a, bb);
    for (int mm = 32; mm >= 1; mm >>= 1) m = fmaxf(m, __shfl_xor(m, mm));
    float ea = expf(a - m);
    float eb = (lane < 16) ? expf(bb - m) : 0.f;
    float ssum = ea + eb;
    for (int mm = 32; mm >= 1; mm >>= 1) ssum += __shfl_xor(ssum, mm);
    float inv = 1.f / ssum;
    lg[h][sq][lane] = ea * inv;
    if (lane < 16) lg[h][sq][64 + lane] = eb * inv;
  }
  __syncthreads();

  // PV: thread = (half, sq, c); V rows read coalesced from global
  {
    const int c = tid & 63, j = tid >> 6;
    const int sq = j & 1, half = j >> 1;
    const float* vbase = v_t + ((size_t)b * T) * 64 + c;
    const int hh = c >> 4;
    float acc = 0.f;
#pragma unroll 4
    for (int cc = 0; cc < 40; ++cc) {
      int col = half * 40 + cc;
      int t = sl[col >> 1] * 2 + (col & 1);
      acc += lg[hh][sq][col] * vbase[(size_t)t * 64];
    }
    part[half][sq][c] = acc;
  }
  __syncthreads();

  if (tid < 128) {
    int sq = tid >> 6, c = tid & 63;
    float o = part[0][sq][c] + part[1][sq][c];
    float lep = lepe_b[c];
#pragma unroll
    for (int kk = 0; kk < 3; ++kk) lep += lepe_w[c * 3 + kk] * vl[sq + kk][c];
    o_t[((size_t)(b * T + 2 * r + sq)) * 64 + c] = o + lep;
  }
}

// ---------------------------------------------------------------- kernel 4: out conv + residual + bn2 + fc1 + relu -> h_c (c-major)
__global__ __launch_bounds__(256) void k_mix(
    const float* __restrict__ x, const float* __restrict__ o_t,
    const float* __restrict__ out_w, const float* __restrict__ out_b,
    const float* __restrict__ n2_g, const float* __restrict__ n2_b,
    const float* __restrict__ fc1_w, const float* __restrict__ bn1_g, const float* __restrict__ bn1_b,
    float* __restrict__ xres, float* __restrict__ h_c)
{
  const int b = blockIdx.y;
  const int t0 = blockIdx.x * 16;
  const int tid = threadIdx.x;
  const float INVS = bnscale();

  __shared__ float ol[16][65];
  __shared__ float yn[16][65];
  __shared__ float xl[16][65];
  __shared__ float wo[64][65];    // out_w transposed: wo[cc][c]
  __shared__ float w1[128][65];   // fc1_w natural [cc][c]
  __shared__ float res2[128][17];

  for (int i = tid; i < 1024; i += 256) {
    int tt = i >> 6, c = i & 63;
    ol[tt][c] = o_t[((size_t)(b * T + t0 + tt)) * 64 + c];
  }
  for (int i = tid; i < 1024; i += 256) {
    int c = i >> 4, tt = i & 15;
    xl[tt][c] = x[(size_t)(b * 64 + c) * T + t0 + tt];
  }
  for (int i = tid; i < 4096; i += 256) {
    int c = i >> 6, cc = i & 63;
    wo[cc][c] = out_w[i];
  }
  for (int i = tid; i < 8192; i += 256) {
    int cc = i >> 6, c = i & 63;
    w1[cc][c] = fc1_w[i];
  }
  __syncthreads();

  // out conv: thread = (c, 4 tt's)
  {
    const int c = tid & 63, grp = tid >> 6;
    float a0 = out_b[c], a1 = a0, a2 = a0, a3 = a0;
    for (int cc = 0; cc < 64; ++cc) {
      float wv = wo[cc][c];
      a0 += wv * ol[grp * 4 + 0][cc];
      a1 += wv * ol[grp * 4 + 1][cc];
      a2 += wv * ol[grp * 4 + 2][cc];
      a3 += wv * ol[grp * 4 + 3][cc];
    }
    float g2 = n2_g[c] * INVS, b2 = n2_b[c];
    float av[4] = {a0, a1, a2, a3};
#pragma unroll
    for (int j = 0; j < 4; ++j) {
      int tt = grp * 4 + j;
      float xr = xl[tt][c] + av[j];
      xres[((size_t)(b * T + t0 + tt)) * 64 + c] = xr;
      yn[tt][c] = xr * g2 + b2;
    }
  }
  __syncthreads();

  // fc1 + bn1 + relu: thread = (cc, 8 tt's)
  {
    const int cc = tid & 127, half = tid >> 7;
    float acc[8];
#pragma unroll
    for (int j = 0; j < 8; ++j) acc[j] = 0.f;
    for (int c = 0; c < 64; ++c) {
      float wv = w1[cc][c];
#pragma unroll
      for (int j = 0; j < 8; ++j) acc[j] += wv * yn[half * 8 + j][c];
    }
    float g1 = bn1_g[cc] * INVS, b1 = bn1_b[cc];
#pragma unroll
    for (int j = 0; j < 8; ++j)
      res2[cc][half * 8 + j] = fmaxf(acc[j] * g1 + b1, 0.f);
  }
  __syncthreads();

  for (int i = tid; i < 2048; i += 256) {
    int tt = i & 15, cc = i >> 4;
    h_c[((size_t)(b * 128 + cc)) * T + t0 + tt] = res2[cc][tt];
  }
}

// ---------------------------------------------------------------- kernel 5: FFT(DIF) -> diag filter + relu -> iFFT(DIT), c-major I/O
__global__ __launch_bounds__(256) void k_fft(
    const float* __restrict__ h_c, const float* __restrict__ fr, const float* __restrict__ fi,
    const float* __restrict__ frb, const float* __restrict__ fib, float* __restrict__ g_c)
{
  const int b = blockIdx.y;
  const int c2 = blockIdx.x;
  const int tid = threadIdx.x;

  __shared__ float re[2048];
  __shared__ float im[2048];
  __shared__ float twr[1024];
  __shared__ float twi[1024];

  for (int i = tid; i < 1024; i += 256) {
    float ang = -6.283185307179586f * (float)i * (1.0f / 2048.0f);
    float sn, cs;
    sincosf(ang, &sn, &cs);
    twr[i] = cs; twi[i] = sn;
  }
  const float* hrow = h_c + ((size_t)(b * 128 + c2)) * T;
  for (int t = tid; t < 2048; t += 256) {
    re[t] = hrow[t];
    im[t] = 0.f;
  }
  __syncthreads();

  // forward DIF: natural in -> bit-reversed out
  for (int s = 11; s >= 1; --s) {
    const int half = 1 << (s - 1);
    for (int k = tid; k < 1024; k += 256) {
      int pos = k & (half - 1);
      int grp = k >> (s - 1);
      int i0 = (grp << s) + pos;
      int i1 = i0 + half;
      int j = pos << (11 - s);
      float wr = twr[j], wi = twi[j];
      float ur = re[i0], ui = im[i0];
      float vr = re[i1], vi = im[i1];
      re[i0] = ur + vr; im[i0] = ui + vi;
      float dr = ur - vr, di = ui - vi;
      re[i1] = dr * wr - di * wi;
      im[i1] = dr * wi + di * wr;
    }
    __syncthreads();
  }

  // elementwise spectral filter (order-independent)
  const float SC = 0.022097086912079608f; // 1/sqrt(2048)
  const float fa = fr[c2 * 129];
  const float fb = fi[c2 * 129];
  const float fra = frb[c2];
  const float fia = fib[c2];
  for (int t = tid; t < 2048; t += 256) {
    float rr = re[t] * SC, ii = im[t] * SC;
    re[t] = fmaxf(rr * fa - ii * fb + fra, 0.f);
    im[t] = fmaxf(ii * fa + rr * fb + fia, 0.f);
  }
  __syncthreads();

  // inverse DIT: bit-reversed in -> natural out
  for (int s = 1; s <= 11; ++s) {
    const int half = 1 << (s - 1);
    for (int k = tid; k < 1024; k += 256) {
      int pos = k & (half - 1);
      int grp = k >> (s - 1);
      int i0 = (grp << s) + pos;
      int i1 = i0 + half;
      int j = pos << (11 - s);
      float wr = twr[j], wi = -twi[j];
      float xr = re[i1], xi = im[i1];
      float tr = xr * wr - xi * wi;
      float ti = xr * wi + xi * wr;
      float ur = re[i0], ui = im[i0];
      re[i0] = ur + tr; im[i0] = ui + ti;
      re[i1] = ur - tr; im[i1] = ui - ti;
    }
    __syncthreads();
  }

  float* grow = g_c + ((size_t)(b * 128 + c2)) * T;
  for (int t = tid; t < 2048; t += 256)
    grow[t] = re[t] * SC;
}

// ---------------------------------------------------------------- kernel 6: fc2 + bn + final residual -> d_out (B,64,T)
__global__ __launch_bounds__(256) void k_out(
    const float* __restrict__ g_c, const float* __restrict__ xres,
    const float* __restrict__ fc2_w, const float* __restrict__ bn2_g, const float* __restrict__ bn2_b,
    float* __restrict__ out)
{
  const int b = blockIdx.y;
  const int t0 = blockIdx.x * 16;
  const int tid = threadIdx.x;
  const float INVS = bnscale();

  __shared__ float gl[16][129];
  __shared__ float w2[128][65];   // fc2_w transposed: w2[cc][c]
  __shared__ float res[64][17];

  for (int i = tid; i < 2048; i += 256) {
    int tt = i & 15, cc = i >> 4;
    gl[tt][cc] = g_c[((size_t)(b * 128 + cc)) * T + t0 + tt];
  }
  for (int i = tid; i < 8192; i += 256) {
    int c = i >> 7, cc = i & 127;
    w2[cc][c] = fc2_w[i];
  }
  __syncthreads();

  {
    const int c = tid & 63, grp = tid >> 6;
    float a0 = 0.f, a1 = 0.f, a2 = 0.f, a3 = 0.f;
    for (int cc = 0; cc < 128; ++cc) {
      float wv = w2[cc][c];
      a0 += wv * gl[grp * 4 + 0][cc];
      a1 += wv * gl[grp * 4 + 1][cc];
      a2 += wv * gl[grp * 4 + 2][cc];
      a3 += wv * gl[grp * 4 + 3][cc];
    }
    float g2 = bn2_g[c] * INVS, b2 = bn2_b[c];
    float av[4] = {a0, a1, a2, a3};
#pragma unroll
    for (int j = 0; j < 4; ++j) {
      int tt = grp * 4 + j;
      res[c][tt] = xres[((size_t)(b * T + t0 + tt)) * 64 + c] + av[j] * g2 + b2;
    }
  }
  __syncthreads();

  for (int i = tid; i < 1024; i += 256) {
    int tt = i & 15, c = i >> 4;
    out[(size_t)(b * 64 + c) * T + t0 + tt] = res[c][tt];
  }
}

// ----------------------------------------------------------------
extern "C" void kernel_launch(void* const* d_in, const int* in_sizes, int n_in,
                              void* d_out, int out_size, void* d_ws, size_t ws_size,
                              hipStream_t stream) {
  (void)in_sizes; (void)n_in; (void)out_size; (void)ws_size;
  const float* x     = (const float*)d_in[0];
  const float* n1_g  = (const float*)d_in[1];
  const float* n1_b  = (const float*)d_in[2];
  const float* wq    = (const float*)d_in[3];
  const float* bnq_g = (const float*)d_in[4];
  const float* bnq_b = (const float*)d_in[5];
  const float* wk    = (const float*)d_in[6];
  const float* bnk_g = (const float*)d_in[7];
  const float* bnk_b = (const float*)d_in[8];
  const float* wv    = (const float*)d_in[9];
  const float* lepe_w= (const float*)d_in[10];
  const float* lepe_b= (const float*)d_in[11];
  const float* out_w = (const float*)d_in[12];
  const float* out_b = (const float*)d_in[13];
  const float* n2_g  = (const float*)d_in[14];
  const float* n2_b  = (const float*)d_in[15];
  const float* fc1_w = (const float*)d_in[16];
  const float* bn1_g = (const float*)d_in[17];
  const float* bn1_b = (const float*)d_in[18];
  const float* fr    = (const float*)d_in[19];
  const float* fi    = (const float*)d_in[20];
  const float* frb   = (const float*)d_in[21];
  const float* fib   = (const float*)d_in[22];
  const float* fc2_w = (const float*)d_in[23];
  const float* bn2_g = (const float*)d_in[24];
  const float* bn2_b = (const float*)d_in[25];

  float* out = (float*)d_out;
  float* ws  = (float*)d_ws;
  const size_t M1 = (size_t)1 << 20;

  float* q_t  = ws;            // 2M floats
  float* k_t  = ws + 2 * M1;   // 2M
  float* v_t  = ws + 4 * M1;   // 2M
  float* q_rc = ws + 6 * M1;   // 1M  (c-major [b][c][r])
  float* k_rc = ws + 7 * M1;   // 1M
  float* o_t  = ws + 8 * M1;   // 2M
  float* xrs  = ws + 10 * M1;  // 2M
  int*   sel  = (int*)(ws + 12 * M1); // 0.64M ints
  float* h_c  = ws;            // 4M c-major [b][cc][t], reuses q_t+k_t (dead after k_attn)
  float* g_c  = ws + 4 * M1;   // 4M c-major, reuses v_t+q_rc+k_rc

  k_qkv<<<dim3(32, 16), 256, 0, stream>>>(x, n1_g, n1_b, wq, bnq_g, bnq_b,
                                          wk, bnk_g, bnk_b, wv, q_t, k_t, v_t, q_rc, k_rc);
  k_scores<<<dim3(256, 16), 256, 0, stream>>>(q_rc, k_rc, sel);
  k_attn<<<dim3(1024, 16), 256, 0, stream>>>(q_t, k_t, v_t, sel, lepe_w, lepe_b, o_t);
  k_mix<<<dim3(128, 16), 256, 0, stream>>>(x, o_t, out_w, out_b, n2_g, n2_b,
                                           fc1_w, bn1_g, bn1_b, xrs, h_c);
  k_fft<<<dim3(128, 16), 256, 0, stream>>>(h_c, fr, fi, frb, fib, g_c);
  k_out<<<dim3(128, 16), 256, 0, stream>>>(g_c, xrs, fc2_w, bn2_g, bn2_b, out);
}

// Round 7
// 540.554 us; speedup vs baseline: 1.3241x; 1.1026x over previous
//
#include <hip/hip_runtime.h>
#include <hip/hip_bf16.h>

#define T 2048
#define NR 1024
#define TOPK 40

static __device__ __forceinline__ float bnscale() { return 0.9999950000374997f; } // 1/sqrt(1+1e-5)

// wave64 unsigned max via DPP (VALU pipe only), broadcast via readlane(63)
static __device__ __forceinline__ unsigned wave_umax64(unsigned x) {
  unsigned r = x, t;
  t = (unsigned)__builtin_amdgcn_update_dpp((int)r, (int)r, 0x111, 0xf, 0xf, false); r = r > t ? r : t; // row_shr:1
  t = (unsigned)__builtin_amdgcn_update_dpp((int)r, (int)r, 0x112, 0xf, 0xf, false); r = r > t ? r : t; // row_shr:2
  t = (unsigned)__builtin_amdgcn_update_dpp((int)r, (int)r, 0x114, 0xf, 0xf, false); r = r > t ? r : t; // row_shr:4
  t = (unsigned)__builtin_amdgcn_update_dpp((int)r, (int)r, 0x118, 0xf, 0xf, false); r = r > t ? r : t; // row_shr:8
  t = (unsigned)__builtin_amdgcn_update_dpp((int)r, (int)r, 0x142, 0xf, 0xf, false); r = r > t ? r : t; // row_bcast:15
  t = (unsigned)__builtin_amdgcn_update_dpp((int)r, (int)r, 0x143, 0xf, 0xf, false); r = r > t ? r : t; // row_bcast:31
  return (unsigned)__builtin_amdgcn_readlane((int)r, 63);
}

// ---------------------------------------------------------------- kernel 1: bn -> conv q,k (k=3) + v (k=1)
// t-major q_t/k_t/v_t + c-major region means q_rc/k_rc
__global__ __launch_bounds__(256) void k_qkv(
    const float* __restrict__ x, const float* __restrict__ n1_g, const float* __restrict__ n1_b,
    const float* __restrict__ wq, const float* __restrict__ bnq_g, const float* __restrict__ bnq_b,
    const float* __restrict__ wk, const float* __restrict__ bnk_g, const float* __restrict__ bnk_b,
    const float* __restrict__ wv,
    float* __restrict__ q_t, float* __restrict__ k_t, float* __restrict__ v_t,
    float* __restrict__ q_rc, float* __restrict__ k_rc)
{
  const int b = blockIdx.y;
  const int t0 = blockIdx.x * 64;
  const int r0 = blockIdx.x * 32;
  const int tid = threadIdx.x;
  const float INVS = bnscale();

  __shared__ float xn[64][67];   // [c][tt], tt covers t0-1 .. t0+64 (pad 67: stride 3 mod 32)
  __shared__ float ot[64][67];   // [c_out][t_local]

  for (int i = tid; i < 64 * 66; i += 256) {
    int c = i / 66, tt = i - c * 66;
    int t = t0 + tt - 1;
    float v = (t >= 0 && t < T) ? x[(size_t)(b * 64 + c) * T + t] : 0.f;
    xn[c][tt] = v * (n1_g[c] * INVS) + n1_b[c];
  }
  __syncthreads();

  const int w = tid >> 6, lane = tid & 63;
  const int ob = __builtin_amdgcn_readfirstlane(w);   // wave-uniform out-channel base -> SGPR weight loads

  float accq[16], acck[16], accv[16];
#pragma unroll
  for (int j = 0; j < 16; ++j) { accq[j] = 0.f; acck[j] = 0.f; accv[j] = 0.f; }

#pragma unroll 1
  for (int c0 = 0; c0 < 64; c0 += 4) {
    float xr[4][3];
#pragma unroll
    for (int cc = 0; cc < 4; ++cc) {
      xr[cc][0] = xn[c0 + cc][lane];
      xr[cc][1] = xn[c0 + cc][lane + 1];
      xr[cc][2] = xn[c0 + cc][lane + 2];
    }
#pragma unroll
    for (int o16 = 0; o16 < 16; ++o16) {
      int o = ob + (o16 << 2);
      const float* wqo = wq + o * 192 + c0 * 3;
      const float* wko = wk + o * 192 + c0 * 3;
      const float* wvo = wv + o * 64 + c0;
      float aq = accq[o16], ak = acck[o16], av = accv[o16];
#pragma unroll
      for (int cc = 0; cc < 4; ++cc) {
        aq += xr[cc][0] * wqo[cc * 3 + 0] + xr[cc][1] * wqo[cc * 3 + 1] + xr[cc][2] * wqo[cc * 3 + 2];
        ak += xr[cc][0] * wko[cc * 3 + 0] + xr[cc][1] * wko[cc * 3 + 1] + xr[cc][2] * wko[cc * 3 + 2];
        av += xr[cc][1] * wvo[cc];
      }
      accq[o16] = aq; acck[o16] = ak; accv[o16] = av;
    }
  }

  // ---- Q: bn, transpose-store, region means ----
#pragma unroll
  for (int o16 = 0; o16 < 16; ++o16) {
    int o = ob + (o16 << 2);
    ot[o][lane] = accq[o16] * (bnq_g[o] * INVS) + bnq_b[o];
  }
  __syncthreads();
  for (int i = tid; i < 4096; i += 256) {
    int c = i & 63, tt = i >> 6;
    q_t[((size_t)(b * T + t0 + tt)) * 64 + c] = ot[c][tt];
  }
  for (int i = tid; i < 2048; i += 256) {
    int rr = i & 31, c = i >> 5;
    q_rc[((size_t)(b * 64 + c)) * NR + r0 + rr] = 0.5f * (ot[c][2 * rr] + ot[c][2 * rr + 1]);
  }
  __syncthreads();

  // ---- K ----
#pragma unroll
  for (int o16 = 0; o16 < 16; ++o16) {
    int o = ob + (o16 << 2);
    ot[o][lane] = acck[o16] * (bnk_g[o] * INVS) + bnk_b[o];
  }
  __syncthreads();
  for (int i = tid; i < 4096; i += 256) {
    int c = i & 63, tt = i >> 6;
    k_t[((size_t)(b * T + t0 + tt)) * 64 + c] = ot[c][tt];
  }
  for (int i = tid; i < 2048; i += 256) {
    int rr = i & 31, c = i >> 5;
    k_rc[((size_t)(b * 64 + c)) * NR + r0 + rr] = 0.5f * (ot[c][2 * rr] + ot[c][2 * rr + 1]);
  }
  __syncthreads();

  // ---- V ----
#pragma unroll
  for (int o16 = 0; o16 < 16; ++o16) {
    int o = ob + (o16 << 2);
    ot[o][lane] = accv[o16];
  }
  __syncthreads();
  for (int i = tid; i < 4096; i += 256) {
    int c = i & 63, tt = i >> 6;
    v_t[((size_t)(b * T + t0 + tt)) * 64 + c] = ot[c][tt];
  }
}

// ---------------------------------------------------------------- kernel 2: region scores + top-40
// 16 rows/block, 4 rows/wave (K amortized 4x). Register GEMM -> packed u32 sort-16 per row ->
// DPP umax serial-40 with in-register shift-down refill (no LDS, no DS ops in the hot loop).
__global__ __launch_bounds__(256) void k_scores(
    const float* __restrict__ q_rc, const float* __restrict__ k_rc, int* __restrict__ sel)
{
  const int b = blockIdx.y;
  const int r0 = blockIdx.x * 16;
  const int tid = threadIdx.x;
  const int w = tid >> 6, lane = tid & 63;

  __shared__ float qsT[16][68];   // [row][c], pad 68 keeps float4 alignment, 2-way banks (free)

  for (int i = tid; i < 1024; i += 256) {
    int rr = i & 15, c = i >> 4;
    qsT[rr][c] = q_rc[((size_t)(b * 64 + c)) * NR + r0 + rr];
  }
  __syncthreads();

  const int row0 = w * 4;

  // ---- GEMM: wave computes rows r0+row0..+3; lane holds cols {256j + 4lane + s}
  float4 acc[4][4];
#pragma unroll
  for (int r = 0; r < 4; ++r)
#pragma unroll
    for (int j = 0; j < 4; ++j) acc[r][j] = make_float4(0.f, 0.f, 0.f, 0.f);

  const float4* kp = (const float4*)(k_rc + ((size_t)b * 64) * NR);
#pragma unroll 1
  for (int c0 = 0; c0 < 64; c0 += 4) {
    float4 qv[4];
#pragma unroll
    for (int r = 0; r < 4; ++r) qv[r] = *(const float4*)&qsT[row0 + r][c0];
#pragma unroll
    for (int cc = 0; cc < 4; ++cc) {
      const float4* kr = kp + (size_t)(c0 + cc) * 256 + lane;
      float4 k0 = kr[0], k1 = kr[64], k2 = kr[128], k3 = kr[192];
      float qf[4] = { (&qv[0].x)[cc], (&qv[1].x)[cc], (&qv[2].x)[cc], (&qv[3].x)[cc] };
#pragma unroll
      for (int r = 0; r < 4; ++r) {
        float q = qf[r];
        acc[r][0].x += q * k0.x; acc[r][0].y += q * k0.y; acc[r][0].z += q * k0.z; acc[r][0].w += q * k0.w;
        acc[r][1].x += q * k1.x; acc[r][1].y += q * k1.y; acc[r][1].z += q * k1.z; acc[r][1].w += q * k1.w;
        acc[r][2].x += q * k2.x; acc[r][2].y += q * k2.y; acc[r][2].z += q * k2.z; acc[r][2].w += q * k2.w;
        acc[r][3].x += q * k3.x; acc[r][3].y += q * k3.y; acc[r][3].z += q * k3.z; acc[r][3].w += q * k3.w;
      }
    }
  }

  // ---- pack to sortable u32 (hi 22 = score, lo 10 = 1023-idx) and bitonic-sort-16 descending per row
  unsigned pk[4][16];
#pragma unroll
  for (int r = 0; r < 4; ++r) {
#pragma unroll
    for (int j = 0; j < 4; ++j) {
      const float* av = &acc[r][j].x;
#pragma unroll
      for (int s = 0; s < 4; ++s) {
        unsigned u = __float_as_uint(av[s]);
        u ^= (unsigned)((int)u >> 31) | 0x80000000u;
        int idx = 256 * j + 4 * lane + s;
        pk[r][4 * j + s] = (u & 0xFFFFFC00u) | (unsigned)(1023 - idx);
      }
    }
#pragma unroll
    for (int k = 2; k <= 16; k <<= 1) {
#pragma unroll
      for (int j = k >> 1; j > 0; j >>= 1) {
#pragma unroll
        for (int i = 0; i < 16; ++i) {
          int l = i ^ j;
          if (l > i) {
            unsigned hi = pk[r][i] > pk[r][l] ? pk[r][i] : pk[r][l];
            unsigned lo = pk[r][i] > pk[r][l] ? pk[r][l] : pk[r][i];
            bool dir = ((i & k) == 0);
            pk[r][i] = dir ? hi : lo;
            pk[r][l] = dir ? lo : hi;
          }
        }
      }
    }
  }

  // ---- serial top-40, 4 independent row chains interleaved; winner shifts its sorted list down.
  // bv is wave-uniform (readlane-broadcast); lane `it` captures it via predicated move.
  int res[4] = {0, 0, 0, 0};
#pragma unroll 1
  for (int it = 0; it < TOPK; ++it) {
#pragma unroll
    for (int r = 0; r < 4; ++r) {
      unsigned bv = wave_umax64(pk[r][0]);
      if (lane == it) res[r] = 1023 - (int)(bv & 1023u);
      bool won = (pk[r][0] == bv);   // exactly one lane matches (unique low bits)
#pragma unroll
      for (int s = 0; s < 15; ++s) pk[r][s] = won ? pk[r][s + 1] : pk[r][s];
      pk[r][15] = won ? 0u : pk[r][15];
    }
  }

  if (lane < TOPK) {
#pragma unroll
    for (int r = 0; r < 4; ++r)
      sel[((size_t)(b * NR + r0 + row0 + r)) * TOPK + lane] = res[r];
  }
}

// ---------------------------------------------------------------- kernel 3: gathered attention + lepe depthwise + bias
// K staged in LDS; V consumed directly from global (coalesced row reads); ~26KB LDS -> 6 blocks/CU
__global__ __launch_bounds__(256) void k_attn(
    const float* __restrict__ q_t, const float* __restrict__ k_t, const float* __restrict__ v_t,
    const int* __restrict__ sel, const float* __restrict__ lepe_w, const float* __restrict__ lepe_b,
    float* __restrict__ o_t)
{
  const int b = blockIdx.y;
  const int r = blockIdx.x;
  const int tid = threadIdx.x;

  __shared__ float kg[80][65];      // gathered K, 20.8 KB
  __shared__ float qb[2][64];
  __shared__ int   sl[40];
  __shared__ float lg[4][2][84];    // probs per head
  __shared__ float vl[4][64];       // v rows 2r-1..2r+2 for lepe
  __shared__ float part[2][2][64];  // PV partials [half][sq][c]

  if (tid < 40) sl[tid] = sel[((size_t)(b * NR + r)) * TOPK + tid];
  if (tid >= 128 && tid < 256) {
    int i = tid - 128;
    int s = i >> 6, c = i & 63;
    qb[s][c] = q_t[((size_t)(b * T + r * 2 + s)) * 64 + c];
  }
  {
    int idx = tid >> 6, c = tid & 63;
    int t = 2 * r - 1 + idx;
    vl[idx][c] = (t >= 0 && t < T) ? v_t[((size_t)(b * T + t)) * 64 + c] : 0.f;
  }
  __syncthreads();

  for (int i = tid; i < 80 * 64; i += 256) {
    int row = i >> 6, c = i & 63;
    int t = sl[row >> 1] * 2 + (row & 1);
    kg[row][c] = k_t[((size_t)(b * T + t)) * 64 + c];
  }
  __syncthreads();

  const int h = tid >> 6, lane = tid & 63;

  // QK^T: wave h computes its head's 2x80 logits
  for (int flat = lane; flat < 160; flat += 64) {
    int sq = flat / 80;
    int col = flat - sq * 80;
    float acc = 0.f;
#pragma unroll
    for (int d = 0; d < 16; ++d) acc += qb[sq][h * 16 + d] * kg[col][h * 16 + d];
    lg[h][sq][col] = acc * 0.125f;  // 64^-0.5
  }

  // softmax (wave-local: lg[h] written and read by wave h only)
  for (int sq = 0; sq < 2; ++sq) {
    float a = lg[h][sq][lane];
    float bb = (lane < 16) ? lg[h][sq][64 + lane] : -INFINITY;
    float m = fmaxf(a, bb);
    for (int mm = 32; mm >= 1; mm >>= 1) m = fmaxf(m, __shfl_xor(m, mm));
    float ea = expf(a - m);
    float eb = (lane < 16) ? expf(bb - m) : 0.f;
    float ssum = ea + eb;
    for (int mm = 32; mm >= 1; mm >>= 1) ssum += __shfl_xor(ssum, mm);
    float inv = 1.f / ssum;
    lg[h][sq][lane] = ea * inv;
    if (lane < 16) lg[h][sq][64 + lane] = eb * inv;
  }
  __syncthreads();

  // PV: thread = (half, sq, c); V rows read coalesced from global
  {
    const int c = tid & 63, j = tid >> 6;
    const int sq = j & 1, half = j >> 1;
    const float* vbase = v_t + ((size_t)b * T) * 64 + c;
    const int hh = c >> 4;
    float acc = 0.f;
#pragma unroll 4
    for (int cc = 0; cc < 40; ++cc) {
      int col = half * 40 + cc;
      int t = sl[col >> 1] * 2 + (col & 1);
      acc += lg[hh][sq][col] * vbase[(size_t)t * 64];
    }
    part[half][sq][c] = acc;
  }
  __syncthreads();

  if (tid < 128) {
    int sq = tid >> 6, c = tid & 63;
    float o = part[0][sq][c] + part[1][sq][c];
    float lep = lepe_b[c];
#pragma unroll
    for (int kk = 0; kk < 3; ++kk) lep += lepe_w[c * 3 + kk] * vl[sq + kk][c];
    o_t[((size_t)(b * T + 2 * r + sq)) * 64 + c] = o + lep;
  }
}

// ---------------------------------------------------------------- kernel 4: out conv + residual + bn2 + fc1 + relu -> h_c (c-major)
__global__ __launch_bounds__(256) void k_mix(
    const float* __restrict__ x, const float* __restrict__ o_t,
    const float* __restrict__ out_w, const float* __restrict__ out_b,
    const float* __restrict__ n2_g, const float* __restrict__ n2_b,
    const float* __restrict__ fc1_w, const float* __restrict__ bn1_g, const float* __restrict__ bn1_b,
    float* __restrict__ xres, float* __restrict__ h_c)
{
  const int b = blockIdx.y;
  const int t0 = blockIdx.x * 16;
  const int tid = threadIdx.x;
  const float INVS = bnscale();

  __shared__ float ol[16][65];
  __shared__ float yn[16][65];
  __shared__ float xl[16][65];
  __shared__ float wo[64][65];    // out_w transposed: wo[cc][c]
  __shared__ float w1[128][65];   // fc1_w natural [cc][c]
  __shared__ float res2[128][17];

  for (int i = tid; i < 1024; i += 256) {
    int tt = i >> 6, c = i & 63;
    ol[tt][c] = o_t[((size_t)(b * T + t0 + tt)) * 64 + c];
  }
  for (int i = tid; i < 1024; i += 256) {
    int c = i >> 4, tt = i & 15;
    xl[tt][c] = x[(size_t)(b * 64 + c) * T + t0 + tt];
  }
  for (int i = tid; i < 4096; i += 256) {
    int c = i >> 6, cc = i & 63;
    wo[cc][c] = out_w[i];
  }
  for (int i = tid; i < 8192; i += 256) {
    int cc = i >> 6, c = i & 63;
    w1[cc][c] = fc1_w[i];
  }
  __syncthreads();

  // out conv: thread = (c, 4 tt's)
  {
    const int c = tid & 63, grp = tid >> 6;
    float a0 = out_b[c], a1 = a0, a2 = a0, a3 = a0;
    for (int cc = 0; cc < 64; ++cc) {
      float wv = wo[cc][c];
      a0 += wv * ol[grp * 4 + 0][cc];
      a1 += wv * ol[grp * 4 + 1][cc];
      a2 += wv * ol[grp * 4 + 2][cc];
      a3 += wv * ol[grp * 4 + 3][cc];
    }
    float g2 = n2_g[c] * INVS, b2 = n2_b[c];
    float av[4] = {a0, a1, a2, a3};
#pragma unroll
    for (int j = 0; j < 4; ++j) {
      int tt = grp * 4 + j;
      float xr = xl[tt][c] + av[j];
      xres[((size_t)(b * T + t0 + tt)) * 64 + c] = xr;
      yn[tt][c] = xr * g2 + b2;
    }
  }
  __syncthreads();

  // fc1 + bn1 + relu: thread = (cc, 8 tt's)
  {
    const int cc = tid & 127, half = tid >> 7;
    float acc[8];
#pragma unroll
    for (int j = 0; j < 8; ++j) acc[j] = 0.f;
    for (int c = 0; c < 64; ++c) {
      float wv = w1[cc][c];
#pragma unroll
      for (int j = 0; j < 8; ++j) acc[j] += wv * yn[half * 8 + j][c];
    }
    float g1 = bn1_g[cc] * INVS, b1 = bn1_b[cc];
#pragma unroll
    for (int j = 0; j < 8; ++j)
      res2[cc][half * 8 + j] = fmaxf(acc[j] * g1 + b1, 0.f);
  }
  __syncthreads();

  for (int i = tid; i < 2048; i += 256) {
    int tt = i & 15, cc = i >> 4;
    h_c[((size_t)(b * 128 + cc)) * T + t0 + tt] = res2[cc][tt];
  }
}

// ---------------------------------------------------------------- kernel 5: FFT(DIF) -> diag filter + relu -> iFFT(DIT), c-major I/O
__global__ __launch_bounds__(256) void k_fft(
    const float* __restrict__ h_c, const float* __restrict__ fr, const float* __restrict__ fi,
    const float* __restrict__ frb, const float* __restrict__ fib, float* __restrict__ g_c)
{
  const int b = blockIdx.y;
  const int c2 = blockIdx.x;
  const int tid = threadIdx.x;

  __shared__ float re[2048];
  __shared__ float im[2048];
  __shared__ float twr[1024];
  __shared__ float twi[1024];

  for (int i = tid; i < 1024; i += 256) {
    float ang = -6.283185307179586f * (float)i * (1.0f / 2048.0f);
    float sn, cs;
    sincosf(ang, &sn, &cs);
    twr[i] = cs; twi[i] = sn;
  }
  const float* hrow = h_c + ((size_t)(b * 128 + c2)) * T;
  for (int t = tid; t < 2048; t += 256) {
    re[t] = hrow[t];
    im[t] = 0.f;
  }
  __syncthreads();

  // forward DIF: natural in -> bit-reversed out
  for (int s = 11; s >= 1; --s) {
    const int half = 1 << (s - 1);
    for (int k = tid; k < 1024; k += 256) {
      int pos = k & (half - 1);
      int grp = k >> (s - 1);
      int i0 = (grp << s) + pos;
      int i1 = i0 + half;
      int j = pos << (11 - s);
      float wr = twr[j], wi = twi[j];
      float ur = re[i0], ui = im[i0];
      float vr = re[i1], vi = im[i1];
      re[i0] = ur + vr; im[i0] = ui + vi;
      float dr = ur - vr, di = ui - vi;
      re[i1] = dr * wr - di * wi;
      im[i1] = dr * wi + di * wr;
    }
    __syncthreads();
  }

  // elementwise spectral filter (order-independent)
  const float SC = 0.022097086912079608f; // 1/sqrt(2048)
  const float fa = fr[c2 * 129];
  const float fb = fi[c2 * 129];
  const float fra = frb[c2];
  const float fia = fib[c2];
  for (int t = tid; t < 2048; t += 256) {
    float rr = re[t] * SC, ii = im[t] * SC;
    re[t] = fmaxf(rr * fa - ii * fb + fra, 0.f);
    im[t] = fmaxf(ii * fa + rr * fb + fia, 0.f);
  }
  __syncthreads();

  // inverse DIT: bit-reversed in -> natural out
  for (int s = 1; s <= 11; ++s) {
    const int half = 1 << (s - 1);
    for (int k = tid; k < 1024; k += 256) {
      int pos = k & (half - 1);
      int grp = k >> (s - 1);
      int i0 = (grp << s) + pos;
      int i1 = i0 + half;
      int j = pos << (11 - s);
      float wr = twr[j], wi = -twi[j];
      float xr = re[i1], xi = im[i1];
      float tr = xr * wr - xi * wi;
      float ti = xr * wi + xi * wr;
      float ur = re[i0], ui = im[i0];
      re[i0] = ur + tr; im[i0] = ui + ti;
      re[i1] = ur - tr; im[i1] = ui - ti;
    }
    __syncthreads();
  }

  float* grow = g_c + ((size_t)(b * 128 + c2)) * T;
  for (int t = tid; t < 2048; t += 256)
    grow[t] = re[t] * SC;
}

// ---------------------------------------------------------------- kernel 6: fc2 + bn + final residual -> d_out (B,64,T)
__global__ __launch_bounds__(256) void k_out(
    const float* __restrict__ g_c, const float* __restrict__ xres,
    const float* __restrict__ fc2_w, const float* __restrict__ bn2_g, const float* __restrict__ bn2_b,
    float* __restrict__ out)
{
  const int b = blockIdx.y;
  const int t0 = blockIdx.x * 16;
  const int tid = threadIdx.x;
  const float INVS = bnscale();

  __shared__ float gl[16][129];
  __shared__ float w2[128][65];   // fc2_w transposed: w2[cc][c]
  __shared__ float res[64][17];

  for (int i = tid; i < 2048; i += 256) {
    int tt = i & 15, cc = i >> 4;
    gl[tt][cc] = g_c[((size_t)(b * 128 + cc)) * T + t0 + tt];
  }
  for (int i = tid; i < 8192; i += 256) {
    int c = i >> 7, cc = i & 127;
    w2[cc][c] = fc2_w[i];
  }
  __syncthreads();

  {
    const int c = tid & 63, grp = tid >> 6;
    float a0 = 0.f, a1 = 0.f, a2 = 0.f, a3 = 0.f;
    for (int cc = 0; cc < 128; ++cc) {
      float wv = w2[cc][c];
      a0 += wv * gl[grp * 4 + 0][cc];
      a1 += wv * gl[grp * 4 + 1][cc];
      a2 += wv * gl[grp * 4 + 2][cc];
      a3 += wv * gl[grp * 4 + 3][cc];
    }
    float g2 = bn2_g[c] * INVS, b2 = bn2_b[c];
    float av[4] = {a0, a1, a2, a3};
#pragma unroll
    for (int j = 0; j < 4; ++j) {
      int tt = grp * 4 + j;
      res[c][tt] = xres[((size_t)(b * T + t0 + tt)) * 64 + c] + av[j] * g2 + b2;
    }
  }
  __syncthreads();

  for (int i = tid; i < 1024; i += 256) {
    int tt = i & 15, c = i >> 4;
    out[(size_t)(b * 64 + c) * T + t0 + tt] = res[c][tt];
  }
}

// ----------------------------------------------------------------
extern "C" void kernel_launch(void* const* d_in, const int* in_sizes, int n_in,
                              void* d_out, int out_size, void* d_ws, size_t ws_size,
                              hipStream_t stream) {
  (void)in_sizes; (void)n_in; (void)out_size; (void)ws_size;
  const float* x     = (const float*)d_in[0];
  const float* n1_g  = (const float*)d_in[1];
  const float* n1_b  = (const float*)d_in[2];
  const float* wq    = (const float*)d_in[3];
  const float* bnq_g = (const float*)d_in[4];
  const float* bnq_b = (const float*)d_in[5];
  const float* wk    = (const float*)d_in[6];
  const float* bnk_g = (const float*)d_in[7];
  const float* bnk_b = (const float*)d_in[8];
  const float* wv    = (const float*)d_in[9];
  const float* lepe_w= (const float*)d_in[10];
  const float* lepe_b= (const float*)d_in[11];
  const float* out_w = (const float*)d_in[12];
  const float* out_b = (const float*)d_in[13];
  const float* n2_g  = (const float*)d_in[14];
  const float* n2_b  = (const float*)d_in[15];
  const float* fc1_w = (const float*)d_in[16];
  const float* bn1_g = (const float*)d_in[17];
  const float* bn1_b = (const float*)d_in[18];
  const float* fr    = (const float*)d_in[19];
  const float* fi    = (const float*)d_in[20];
  const float* frb   = (const float*)d_in[21];
  const float* fib   = (const float*)d_in[22];
  const float* fc2_w = (const float*)d_in[23];
  const float* bn2_g = (const float*)d_in[24];
  const float* bn2_b = (const float*)d_in[25];

  float* out = (float*)d_out;
  float* ws  = (float*)d_ws;
  const size_t M1 = (size_t)1 << 20;

  float* q_t  = ws;            // 2M floats
  float* k_t  = ws + 2 * M1;   // 2M
  float* v_t  = ws + 4 * M1;   // 2M
  float* q_rc = ws + 6 * M1;   // 1M  (c-major [b][c][r])
  float* k_rc = ws + 7 * M1;   // 1M
  float* o_t  = ws + 8 * M1;   // 2M
  float* xrs  = ws + 10 * M1;  // 2M
  int*   sel  = (int*)(ws + 12 * M1); // 0.64M ints
  float* h_c  = ws;            // 4M c-major [b][cc][t], reuses q_t+k_t (dead after k_attn)
  float* g_c  = ws + 4 * M1;   // 4M c-major, reuses v_t+q_rc+k_rc

  k_qkv<<<dim3(32, 16), 256, 0, stream>>>(x, n1_g, n1_b, wq, bnq_g, bnq_b,
                                          wk, bnk_g, bnk_b, wv, q_t, k_t, v_t, q_rc, k_rc);
  k_scores<<<dim3(64, 16), 256, 0, stream>>>(q_rc, k_rc, sel);
  k_attn<<<dim3(1024, 16), 256, 0, stream>>>(q_t, k_t, v_t, sel, lepe_w, lepe_b, o_t);
  k_mix<<<dim3(128, 16), 256, 0, stream>>>(x, o_t, out_w, out_b, n2_g, n2_b,
                                           fc1_w, bn1_g, bn1_b, xrs, h_c);
  k_fft<<<dim3(128, 16), 256, 0, stream>>>(h_c, fr, fi, frb, fib, g_c);
  k_out<<<dim3(128, 16), 256, 0, stream>>>(g_c, xrs, fc2_w, bn2_g, bn2_b, out);
}

// Round 8
// 481.308 us; speedup vs baseline: 1.4871x; 1.1231x over previous
//
#include <hip/hip_runtime.h>
#include <hip/hip_bf16.h>

#define T 2048
#define NR 1024
#define TOPK 40

static __device__ __forceinline__ float bnscale() { return 0.9999950000374997f; } // 1/sqrt(1+1e-5)

// wave64 unsigned max via DPP (VALU pipe only), broadcast via readlane(63)
static __device__ __forceinline__ unsigned wave_umax64(unsigned x) {
  unsigned r = x, t;
  t = (unsigned)__builtin_amdgcn_update_dpp((int)r, (int)r, 0x111, 0xf, 0xf, false); r = r > t ? r : t; // row_shr:1
  t = (unsigned)__builtin_amdgcn_update_dpp((int)r, (int)r, 0x112, 0xf, 0xf, false); r = r > t ? r : t; // row_shr:2
  t = (unsigned)__builtin_amdgcn_update_dpp((int)r, (int)r, 0x114, 0xf, 0xf, false); r = r > t ? r : t; // row_shr:4
  t = (unsigned)__builtin_amdgcn_update_dpp((int)r, (int)r, 0x118, 0xf, 0xf, false); r = r > t ? r : t; // row_shr:8
  t = (unsigned)__builtin_amdgcn_update_dpp((int)r, (int)r, 0x142, 0xf, 0xf, false); r = r > t ? r : t; // row_bcast:15
  t = (unsigned)__builtin_amdgcn_update_dpp((int)r, (int)r, 0x143, 0xf, 0xf, false); r = r > t ? r : t; // row_bcast:31
  return (unsigned)__builtin_amdgcn_readlane((int)r, 63);
}

// ---------------------------------------------------------------- kernel 1: bn -> conv q,k (k=3) + v (k=1)
// oc-split: each block computes a 16-channel output slice over a 64-t tile.
// grid.x = 32 tiles * 4 oc-slices -> 2048 blocks total (8 blocks/CU, latency-hiding occupancy).
__global__ __launch_bounds__(256) void k_qkv(
    const float* __restrict__ x, const float* __restrict__ n1_g, const float* __restrict__ n1_b,
    const float* __restrict__ wq, const float* __restrict__ bnq_g, const float* __restrict__ bnq_b,
    const float* __restrict__ wk, const float* __restrict__ bnk_g, const float* __restrict__ bnk_b,
    const float* __restrict__ wv,
    float* __restrict__ q_t, float* __restrict__ k_t, float* __restrict__ v_t,
    float* __restrict__ q_rc, float* __restrict__ k_rc)
{
  const int b = blockIdx.y;
  const int tile = blockIdx.x >> 2;
  const int oc0 = (blockIdx.x & 3) * 16;
  const int t0 = tile * 64;
  const int r0 = tile * 32;
  const int tid = threadIdx.x;
  const float INVS = bnscale();

  __shared__ float xn[64][67];   // [c][tt], tt covers t0-1 .. t0+64
  __shared__ float ot[16][67];   // [oc_local][t_local]

  for (int i = tid; i < 64 * 66; i += 256) {
    int c = i / 66, tt = i - c * 66;
    int t = t0 + tt - 1;
    float v = (t >= 0 && t < T) ? x[(size_t)(b * 64 + c) * T + t] : 0.f;
    xn[c][tt] = v * (n1_g[c] * INVS) + n1_b[c];
  }
  __syncthreads();

  const int w = tid >> 6, lane = tid & 63;
  const int ob = oc0 + __builtin_amdgcn_readfirstlane(w) * 4;  // wave-uniform -> SGPR weight loads

  float accq[4], acck[4], accv[4];
#pragma unroll
  for (int j = 0; j < 4; ++j) { accq[j] = 0.f; acck[j] = 0.f; accv[j] = 0.f; }

#pragma unroll 1
  for (int c0 = 0; c0 < 64; c0 += 4) {
    float xr[4][3];
#pragma unroll
    for (int cc = 0; cc < 4; ++cc) {
      xr[cc][0] = xn[c0 + cc][lane];
      xr[cc][1] = xn[c0 + cc][lane + 1];
      xr[cc][2] = xn[c0 + cc][lane + 2];
    }
#pragma unroll
    for (int o4 = 0; o4 < 4; ++o4) {
      int o = ob + o4;
      const float* wqo = wq + o * 192 + c0 * 3;
      const float* wko = wk + o * 192 + c0 * 3;
      const float* wvo = wv + o * 64 + c0;
      float aq = accq[o4], ak = acck[o4], av = accv[o4];
#pragma unroll
      for (int cc = 0; cc < 4; ++cc) {
        aq += xr[cc][0] * wqo[cc * 3 + 0] + xr[cc][1] * wqo[cc * 3 + 1] + xr[cc][2] * wqo[cc * 3 + 2];
        ak += xr[cc][0] * wko[cc * 3 + 0] + xr[cc][1] * wko[cc * 3 + 1] + xr[cc][2] * wko[cc * 3 + 2];
        av += xr[cc][1] * wvo[cc];
      }
      accq[o4] = aq; acck[o4] = ak; accv[o4] = av;
    }
  }

  // ---- Q: bn, transpose-store slice, region means ----
#pragma unroll
  for (int o4 = 0; o4 < 4; ++o4) {
    int o = ob + o4;
    ot[o - oc0][lane] = accq[o4] * (bnq_g[o] * INVS) + bnq_b[o];
  }
  __syncthreads();
  for (int i = tid; i < 1024; i += 256) {
    int cl = i & 15, tt = i >> 4;
    q_t[((size_t)(b * T + t0 + tt)) * 64 + oc0 + cl] = ot[cl][tt];
  }
  for (int i = tid; i < 512; i += 256) {
    int rr = i & 31, cl = i >> 5;
    q_rc[((size_t)(b * 64 + oc0 + cl)) * NR + r0 + rr] = 0.5f * (ot[cl][2 * rr] + ot[cl][2 * rr + 1]);
  }
  __syncthreads();

  // ---- K ----
#pragma unroll
  for (int o4 = 0; o4 < 4; ++o4) {
    int o = ob + o4;
    ot[o - oc0][lane] = acck[o4] * (bnk_g[o] * INVS) + bnk_b[o];
  }
  __syncthreads();
  for (int i = tid; i < 1024; i += 256) {
    int cl = i & 15, tt = i >> 4;
    k_t[((size_t)(b * T + t0 + tt)) * 64 + oc0 + cl] = ot[cl][tt];
  }
  for (int i = tid; i < 512; i += 256) {
    int rr = i & 31, cl = i >> 5;
    k_rc[((size_t)(b * 64 + oc0 + cl)) * NR + r0 + rr] = 0.5f * (ot[cl][2 * rr] + ot[cl][2 * rr + 1]);
  }
  __syncthreads();

  // ---- V ----
#pragma unroll
  for (int o4 = 0; o4 < 4; ++o4) {
    ot[ob + o4 - oc0][lane] = accv[o4];
  }
  __syncthreads();
  for (int i = tid; i < 1024; i += 256) {
    int cl = i & 15, tt = i >> 4;
    v_t[((size_t)(b * T + t0 + tt)) * 64 + oc0 + cl] = ot[cl][tt];
  }
}

// ---------------------------------------------------------------- kernel 2: region scores + top-40
// 16 rows/block, 4 rows/wave (K amortized 4x). Register GEMM -> packed u32 sort-16 per row ->
// DPP umax serial-40 with in-register shift-down refill (no LDS, no DS ops in the hot loop).
__global__ __launch_bounds__(256) void k_scores(
    const float* __restrict__ q_rc, const float* __restrict__ k_rc, int* __restrict__ sel)
{
  const int b = blockIdx.y;
  const int r0 = blockIdx.x * 16;
  const int tid = threadIdx.x;
  const int w = tid >> 6, lane = tid & 63;

  __shared__ float qsT[16][68];   // [row][c], pad 68 keeps float4 alignment, 2-way banks (free)

  for (int i = tid; i < 1024; i += 256) {
    int rr = i & 15, c = i >> 4;
    qsT[rr][c] = q_rc[((size_t)(b * 64 + c)) * NR + r0 + rr];
  }
  __syncthreads();

  const int row0 = w * 4;

  // ---- GEMM: wave computes rows r0+row0..+3; lane holds cols {256j + 4lane + s}
  float4 acc[4][4];
#pragma unroll
  for (int r = 0; r < 4; ++r)
#pragma unroll
    for (int j = 0; j < 4; ++j) acc[r][j] = make_float4(0.f, 0.f, 0.f, 0.f);

  const float4* kp = (const float4*)(k_rc + ((size_t)b * 64) * NR);
#pragma unroll 1
  for (int c0 = 0; c0 < 64; c0 += 4) {
    float4 qv[4];
#pragma unroll
    for (int r = 0; r < 4; ++r) qv[r] = *(const float4*)&qsT[row0 + r][c0];
#pragma unroll
    for (int cc = 0; cc < 4; ++cc) {
      const float4* kr = kp + (size_t)(c0 + cc) * 256 + lane;
      float4 k0 = kr[0], k1 = kr[64], k2 = kr[128], k3 = kr[192];
      float qf[4] = { (&qv[0].x)[cc], (&qv[1].x)[cc], (&qv[2].x)[cc], (&qv[3].x)[cc] };
#pragma unroll
      for (int r = 0; r < 4; ++r) {
        float q = qf[r];
        acc[r][0].x += q * k0.x; acc[r][0].y += q * k0.y; acc[r][0].z += q * k0.z; acc[r][0].w += q * k0.w;
        acc[r][1].x += q * k1.x; acc[r][1].y += q * k1.y; acc[r][1].z += q * k1.z; acc[r][1].w += q * k1.w;
        acc[r][2].x += q * k2.x; acc[r][2].y += q * k2.y; acc[r][2].z += q * k2.z; acc[r][2].w += q * k2.w;
        acc[r][3].x += q * k3.x; acc[r][3].y += q * k3.y; acc[r][3].z += q * k3.z; acc[r][3].w += q * k3.w;
      }
    }
  }

  // ---- pack to sortable u32 (hi 22 = score, lo 10 = 1023-idx) and bitonic-sort-16 descending per row
  unsigned pk[4][16];
#pragma unroll
  for (int r = 0; r < 4; ++r) {
#pragma unroll
    for (int j = 0; j < 4; ++j) {
      const float* av = &acc[r][j].x;
#pragma unroll
      for (int s = 0; s < 4; ++s) {
        unsigned u = __float_as_uint(av[s]);
        u ^= (unsigned)((int)u >> 31) | 0x80000000u;
        int idx = 256 * j + 4 * lane + s;
        pk[r][4 * j + s] = (u & 0xFFFFFC00u) | (unsigned)(1023 - idx);
      }
    }
#pragma unroll
    for (int k = 2; k <= 16; k <<= 1) {
#pragma unroll
      for (int j = k >> 1; j > 0; j >>= 1) {
#pragma unroll
        for (int i = 0; i < 16; ++i) {
          int l = i ^ j;
          if (l > i) {
            unsigned hi = pk[r][i] > pk[r][l] ? pk[r][i] : pk[r][l];
            unsigned lo = pk[r][i] > pk[r][l] ? pk[r][l] : pk[r][i];
            bool dir = ((i & k) == 0);
            pk[r][i] = dir ? hi : lo;
            pk[r][l] = dir ? lo : hi;
          }
        }
      }
    }
  }

  // ---- serial top-40, 4 independent row chains interleaved; winner shifts its sorted list down.
  // bv is wave-uniform (readlane-broadcast); lane `it` captures it via predicated move.
  int res[4] = {0, 0, 0, 0};
#pragma unroll 1
  for (int it = 0; it < TOPK; ++it) {
#pragma unroll
    for (int r = 0; r < 4; ++r) {
      unsigned bv = wave_umax64(pk[r][0]);
      if (lane == it) res[r] = 1023 - (int)(bv & 1023u);
      bool won = (pk[r][0] == bv);   // exactly one lane matches (unique low bits)
#pragma unroll
      for (int s = 0; s < 15; ++s) pk[r][s] = won ? pk[r][s + 1] : pk[r][s];
      pk[r][15] = won ? 0u : pk[r][15];
    }
  }

  if (lane < TOPK) {
#pragma unroll
    for (int r = 0; r < 4; ++r)
      sel[((size_t)(b * NR + r0 + row0 + r)) * TOPK + lane] = res[r];
  }
}

// ---------------------------------------------------------------- kernel 3: gathered attention + lepe depthwise + bias
// K staged in LDS; V consumed directly from global (coalesced row reads); ~26KB LDS -> 6 blocks/CU
__global__ __launch_bounds__(256) void k_attn(
    const float* __restrict__ q_t, const float* __restrict__ k_t, const float* __restrict__ v_t,
    const int* __restrict__ sel, const float* __restrict__ lepe_w, const float* __restrict__ lepe_b,
    float* __restrict__ o_t)
{
  const int b = blockIdx.y;
  const int r = blockIdx.x;
  const int tid = threadIdx.x;

  __shared__ float kg[80][65];      // gathered K, 20.8 KB
  __shared__ float qb[2][64];
  __shared__ int   sl[40];
  __shared__ float lg[4][2][84];    // probs per head
  __shared__ float vl[4][64];       // v rows 2r-1..2r+2 for lepe
  __shared__ float part[2][2][64];  // PV partials [half][sq][c]

  if (tid < 40) sl[tid] = sel[((size_t)(b * NR + r)) * TOPK + tid];
  if (tid >= 128 && tid < 256) {
    int i = tid - 128;
    int s = i >> 6, c = i & 63;
    qb[s][c] = q_t[((size_t)(b * T + r * 2 + s)) * 64 + c];
  }
  {
    int idx = tid >> 6, c = tid & 63;
    int t = 2 * r - 1 + idx;
    vl[idx][c] = (t >= 0 && t < T) ? v_t[((size_t)(b * T + t)) * 64 + c] : 0.f;
  }
  __syncthreads();

  for (int i = tid; i < 80 * 64; i += 256) {
    int row = i >> 6, c = i & 63;
    int t = sl[row >> 1] * 2 + (row & 1);
    kg[row][c] = k_t[((size_t)(b * T + t)) * 64 + c];
  }
  __syncthreads();

  const int h = tid >> 6, lane = tid & 63;

  // QK^T: wave h computes its head's 2x80 logits
  for (int flat = lane; flat < 160; flat += 64) {
    int sq = flat / 80;
    int col = flat - sq * 80;
    float acc = 0.f;
#pragma unroll
    for (int d = 0; d < 16; ++d) acc += qb[sq][h * 16 + d] * kg[col][h * 16 + d];
    lg[h][sq][col] = acc * 0.125f;  // 64^-0.5
  }

  // softmax (wave-local: lg[h] written and read by wave h only)
  for (int sq = 0; sq < 2; ++sq) {
    float a = lg[h][sq][lane];
    float bb = (lane < 16) ? lg[h][sq][64 + lane] : -INFINITY;
    float m = fmaxf(a, bb);
    for (int mm = 32; mm >= 1; mm >>= 1) m = fmaxf(m, __shfl_xor(m, mm));
    float ea = expf(a - m);
    float eb = (lane < 16) ? expf(bb - m) : 0.f;
    float ssum = ea + eb;
    for (int mm = 32; mm >= 1; mm >>= 1) ssum += __shfl_xor(ssum, mm);
    float inv = 1.f / ssum;
    lg[h][sq][lane] = ea * inv;
    if (lane < 16) lg[h][sq][64 + lane] = eb * inv;
  }
  __syncthreads();

  // PV: thread = (half, sq, c); V rows read coalesced from global
  {
    const int c = tid & 63, j = tid >> 6;
    const int sq = j & 1, half = j >> 1;
    const float* vbase = v_t + ((size_t)b * T) * 64 + c;
    const int hh = c >> 4;
    float acc = 0.f;
#pragma unroll 4
    for (int cc = 0; cc < 40; ++cc) {
      int col = half * 40 + cc;
      int t = sl[col >> 1] * 2 + (col & 1);
      acc += lg[hh][sq][col] * vbase[(size_t)t * 64];
    }
    part[half][sq][c] = acc;
  }
  __syncthreads();

  if (tid < 128) {
    int sq = tid >> 6, c = tid & 63;
    float o = part[0][sq][c] + part[1][sq][c];
    float lep = lepe_b[c];
#pragma unroll
    for (int kk = 0; kk < 3; ++kk) lep += lepe_w[c * 3 + kk] * vl[sq + kk][c];
    o_t[((size_t)(b * T + 2 * r + sq)) * 64 + c] = o + lep;
  }
}

// ---------------------------------------------------------------- kernel 4: out conv + residual + bn2 + fc1 + relu -> h_c (c-major)
__global__ __launch_bounds__(256) void k_mix(
    const float* __restrict__ x, const float* __restrict__ o_t,
    const float* __restrict__ out_w, const float* __restrict__ out_b,
    const float* __restrict__ n2_g, const float* __restrict__ n2_b,
    const float* __restrict__ fc1_w, const float* __restrict__ bn1_g, const float* __restrict__ bn1_b,
    float* __restrict__ xres, float* __restrict__ h_c)
{
  const int b = blockIdx.y;
  const int t0 = blockIdx.x * 16;
  const int tid = threadIdx.x;
  const float INVS = bnscale();

  __shared__ float ol[16][65];
  __shared__ float yn[16][65];
  __shared__ float xl[16][65];
  __shared__ float wo[64][65];    // out_w transposed: wo[cc][c]
  __shared__ float w1[128][65];   // fc1_w natural [cc][c]
  __shared__ float res2[128][17];

  for (int i = tid; i < 1024; i += 256) {
    int tt = i >> 6, c = i & 63;
    ol[tt][c] = o_t[((size_t)(b * T + t0 + tt)) * 64 + c];
  }
  for (int i = tid; i < 1024; i += 256) {
    int c = i >> 4, tt = i & 15;
    xl[tt][c] = x[(size_t)(b * 64 + c) * T + t0 + tt];
  }
  for (int i = tid; i < 4096; i += 256) {
    int c = i >> 6, cc = i & 63;
    wo[cc][c] = out_w[i];
  }
  for (int i = tid; i < 8192; i += 256) {
    int cc = i >> 6, c = i & 63;
    w1[cc][c] = fc1_w[i];
  }
  __syncthreads();

  // out conv: thread = (c, 4 tt's)
  {
    const int c = tid & 63, grp = tid >> 6;
    float a0 = out_b[c], a1 = a0, a2 = a0, a3 = a0;
    for (int cc = 0; cc < 64; ++cc) {
      float wv = wo[cc][c];
      a0 += wv * ol[grp * 4 + 0][cc];
      a1 += wv * ol[grp * 4 + 1][cc];
      a2 += wv * ol[grp * 4 + 2][cc];
      a3 += wv * ol[grp * 4 + 3][cc];
    }
    float g2 = n2_g[c] * INVS, b2 = n2_b[c];
    float av[4] = {a0, a1, a2, a3};
#pragma unroll
    for (int j = 0; j < 4; ++j) {
      int tt = grp * 4 + j;
      float xr = xl[tt][c] + av[j];
      xres[((size_t)(b * T + t0 + tt)) * 64 + c] = xr;
      yn[tt][c] = xr * g2 + b2;
    }
  }
  __syncthreads();

  // fc1 + bn1 + relu: thread = (cc, 8 tt's)
  {
    const int cc = tid & 127, half = tid >> 7;
    float acc[8];
#pragma unroll
    for (int j = 0; j < 8; ++j) acc[j] = 0.f;
    for (int c = 0; c < 64; ++c) {
      float wv = w1[cc][c];
#pragma unroll
      for (int j = 0; j < 8; ++j) acc[j] += wv * yn[half * 8 + j][c];
    }
    float g1 = bn1_g[cc] * INVS, b1 = bn1_b[cc];
#pragma unroll
    for (int j = 0; j < 8; ++j)
      res2[cc][half * 8 + j] = fmaxf(acc[j] * g1 + b1, 0.f);
  }
  __syncthreads();

  for (int i = tid; i < 2048; i += 256) {
    int tt = i & 15, cc = i >> 4;
    h_c[((size_t)(b * 128 + cc)) * T + t0 + tt] = res2[cc][tt];
  }
}

// ---------------------------------------------------------------- kernel 5: FFT(DIF) -> diag filter + relu -> iFFT(DIT), c-major I/O
__global__ __launch_bounds__(256) void k_fft(
    const float* __restrict__ h_c, const float* __restrict__ fr, const float* __restrict__ fi,
    const float* __restrict__ frb, const float* __restrict__ fib, float* __restrict__ g_c)
{
  const int b = blockIdx.y;
  const int c2 = blockIdx.x;
  const int tid = threadIdx.x;

  __shared__ float re[2048];
  __shared__ float im[2048];
  __shared__ float twr[1024];
  __shared__ float twi[1024];

  for (int i = tid; i < 1024; i += 256) {
    float ang = -6.283185307179586f * (float)i * (1.0f / 2048.0f);
    float sn, cs;
    sincosf(ang, &sn, &cs);
    twr[i] = cs; twi[i] = sn;
  }
  const float* hrow = h_c + ((size_t)(b * 128 + c2)) * T;
  for (int t = tid; t < 2048; t += 256) {
    re[t] = hrow[t];
    im[t] = 0.f;
  }
  __syncthreads();

  // forward DIF: natural in -> bit-reversed out
  for (int s = 11; s >= 1; --s) {
    const int half = 1 << (s - 1);
    for (int k = tid; k < 1024; k += 256) {
      int pos = k & (half - 1);
      int grp = k >> (s - 1);
      int i0 = (grp << s) + pos;
      int i1 = i0 + half;
      int j = pos << (11 - s);
      float wr = twr[j], wi = twi[j];
      float ur = re[i0], ui = im[i0];
      float vr = re[i1], vi = im[i1];
      re[i0] = ur + vr; im[i0] = ui + vi;
      float dr = ur - vr, di = ui - vi;
      re[i1] = dr * wr - di * wi;
      im[i1] = dr * wi + di * wr;
    }
    __syncthreads();
  }

  // elementwise spectral filter (order-independent)
  const float SC = 0.022097086912079608f; // 1/sqrt(2048)
  const float fa = fr[c2 * 129];
  const float fb = fi[c2 * 129];
  const float fra = frb[c2];
  const float fia = fib[c2];
  for (int t = tid; t < 2048; t += 256) {
    float rr = re[t] * SC, ii = im[t] * SC;
    re[t] = fmaxf(rr * fa - ii * fb + fra, 0.f);
    im[t] = fmaxf(ii * fa + rr * fb + fia, 0.f);
  }
  __syncthreads();

  // inverse DIT: bit-reversed in -> natural out
  for (int s = 1; s <= 11; ++s) {
    const int half = 1 << (s - 1);
    for (int k = tid; k < 1024; k += 256) {
      int pos = k & (half - 1);
      int grp = k >> (s - 1);
      int i0 = (grp << s) + pos;
      int i1 = i0 + half;
      int j = pos << (11 - s);
      float wr = twr[j], wi = -twi[j];
      float xr = re[i1], xi = im[i1];
      float tr = xr * wr - xi * wi;
      float ti = xr * wi + xi * wr;
      float ur = re[i0], ui = im[i0];
      re[i0] = ur + tr; im[i0] = ui + ti;
      re[i1] = ur - tr; im[i1] = ui - ti;
    }
    __syncthreads();
  }

  float* grow = g_c + ((size_t)(b * 128 + c2)) * T;
  for (int t = tid; t < 2048; t += 256)
    grow[t] = re[t] * SC;
}

// ---------------------------------------------------------------- kernel 6: fc2 + bn + final residual -> d_out (B,64,T)
__global__ __launch_bounds__(256) void k_out(
    const float* __restrict__ g_c, const float* __restrict__ xres,
    const float* __restrict__ fc2_w, const float* __restrict__ bn2_g, const float* __restrict__ bn2_b,
    float* __restrict__ out)
{
  const int b = blockIdx.y;
  const int t0 = blockIdx.x * 16;
  const int tid = threadIdx.x;
  const float INVS = bnscale();

  __shared__ float gl[16][129];
  __shared__ float w2[128][65];   // fc2_w transposed: w2[cc][c]
  __shared__ float res[64][17];

  for (int i = tid; i < 2048; i += 256) {
    int tt = i & 15, cc = i >> 4;
    gl[tt][cc] = g_c[((size_t)(b * 128 + cc)) * T + t0 + tt];
  }
  for (int i = tid; i < 8192; i += 256) {
    int c = i >> 7, cc = i & 127;
    w2[cc][c] = fc2_w[i];
  }
  __syncthreads();

  {
    const int c = tid & 63, grp = tid >> 6;
    float a0 = 0.f, a1 = 0.f, a2 = 0.f, a3 = 0.f;
    for (int cc = 0; cc < 128; ++cc) {
      float wv = w2[cc][c];
      a0 += wv * gl[grp * 4 + 0][cc];
      a1 += wv * gl[grp * 4 + 1][cc];
      a2 += wv * gl[grp * 4 + 2][cc];
      a3 += wv * gl[grp * 4 + 3][cc];
    }
    float g2 = bn2_g[c] * INVS, b2 = bn2_b[c];
    float av[4] = {a0, a1, a2, a3};
#pragma unroll
    for (int j = 0; j < 4; ++j) {
      int tt = grp * 4 + j;
      res[c][tt] = xres[((size_t)(b * T + t0 + tt)) * 64 + c] + av[j] * g2 + b2;
    }
  }
  __syncthreads();

  for (int i = tid; i < 1024; i += 256) {
    int tt = i & 15, c = i >> 4;
    out[(size_t)(b * 64 + c) * T + t0 + tt] = res[c][tt];
  }
}

// ----------------------------------------------------------------
extern "C" void kernel_launch(void* const* d_in, const int* in_sizes, int n_in,
                              void* d_out, int out_size, void* d_ws, size_t ws_size,
                              hipStream_t stream) {
  (void)in_sizes; (void)n_in; (void)out_size; (void)ws_size;
  const float* x     = (const float*)d_in[0];
  const float* n1_g  = (const float*)d_in[1];
  const float* n1_b  = (const float*)d_in[2];
  const float* wq    = (const float*)d_in[3];
  const float* bnq_g = (const float*)d_in[4];
  const float* bnq_b = (const float*)d_in[5];
  const float* wk    = (const float*)d_in[6];
  const float* bnk_g = (const float*)d_in[7];
  const float* bnk_b = (const float*)d_in[8];
  const float* wv    = (const float*)d_in[9];
  const float* lepe_w= (const float*)d_in[10];
  const float* lepe_b= (const float*)d_in[11];
  const float* out_w = (const float*)d_in[12];
  const float* out_b = (const float*)d_in[13];
  const float* n2_g  = (const float*)d_in[14];
  const float* n2_b  = (const float*)d_in[15];
  const float* fc1_w = (const float*)d_in[16];
  const float* bn1_g = (const float*)d_in[17];
  const float* bn1_b = (const float*)d_in[18];
  const float* fr    = (const float*)d_in[19];
  const float* fi    = (const float*)d_in[20];
  const float* frb   = (const float*)d_in[21];
  const float* fib   = (const float*)d_in[22];
  const float* fc2_w = (const float*)d_in[23];
  const float* bn2_g = (const float*)d_in[24];
  const float* bn2_b = (const float*)d_in[25];

  float* out = (float*)d_out;
  float* ws  = (float*)d_ws;
  const size_t M1 = (size_t)1 << 20;

  float* q_t  = ws;            // 2M floats
  float* k_t  = ws + 2 * M1;   // 2M
  float* v_t  = ws + 4 * M1;   // 2M
  float* q_rc = ws + 6 * M1;   // 1M  (c-major [b][c][r])
  float* k_rc = ws + 7 * M1;   // 1M
  float* o_t  = ws + 8 * M1;   // 2M
  float* xrs  = ws + 10 * M1;  // 2M
  int*   sel  = (int*)(ws + 12 * M1); // 0.64M ints
  float* h_c  = ws;            // 4M c-major [b][cc][t], reuses q_t+k_t (dead after k_attn)
  float* g_c  = ws + 4 * M1;   // 4M c-major, reuses v_t+q_rc+k_rc

  k_qkv<<<dim3(128, 16), 256, 0, stream>>>(x, n1_g, n1_b, wq, bnq_g, bnq_b,
                                           wk, bnk_g, bnk_b, wv, q_t, k_t, v_t, q_rc, k_rc);
  k_scores<<<dim3(64, 16), 256, 0, stream>>>(q_rc, k_rc, sel);
  k_attn<<<dim3(1024, 16), 256, 0, stream>>>(q_t, k_t, v_t, sel, lepe_w, lepe_b, o_t);
  k_mix<<<dim3(128, 16), 256, 0, stream>>>(x, o_t, out_w, out_b, n2_g, n2_b,
                                           fc1_w, bn1_g, bn1_b, xrs, h_c);
  k_fft<<<dim3(128, 16), 256, 0, stream>>>(h_c, fr, fi, frb, fib, g_c);
  k_out<<<dim3(128, 16), 256, 0, stream>>>(g_c, xrs, fc2_w, bn2_g, bn2_b, out);
}